// Round 6
// baseline (1598.697 us; speedup 1.0000x reference)
//
#include <hip/hip_runtime.h>
#include <math.h>

// ---------------------------------------------------------------------------
// FancyNet: 4-level hierarchical GNN + MLP head on MI355X.
//   * hW = h @ W_msg per-node (gather commutes with matmul) -> 7x less GEMM
//   * up_l == arange(N_l/2) => downsample = first-half rows; ".at[up].set(hud)"
//     = conditional-source read (j<half ? top : old)
//   * propagation unrolled to 10 prop kernels with ping-pong buffers
//   * BN folds to scale/shift; bn2 folded into Wc' + bias13
//   * R1 fix: NO contended global float atomics (stats via block partials).
//   * R3 fix: deterministic two-level counting-sort CSR build (no global
//     atomics, ~1x write amplification).
//   * R4/R5 lesson: full-row-in-registers GEMM spills to scratch (VGPR=256,
//     FETCH GB/dispatch). ABANDONED; rule #20.
//   * R6: R3-style gemm + 2 rows/thread (ILP x2, ~40 VGPR). 1136us.
//   * R7: grid-axis swap in gemm. R6 counters: FETCH 124MB for a 42MB input
//     (5 col-group re-reads; blocks sharing rows were gridDim.x apart in
//     dispatch order -> L2 evicted between passes). Now col group =
//     blockIdx.x (fast), row block = blockIdx.y: the 4-5 blocks reading the
//     same 512-row slice dispatch back-to-back -> passes 2-5 hit L2/L3.
// ---------------------------------------------------------------------------

#define HID 80
constexpr int cN0 = 131072;

__device__ __forceinline__ float eluf(float x) { return x > 0.f ? x : expm1f(x); }

// ---------------- bn1 stats (6 cols): 2 rows/thread as 3x float4, block partials ----------------
__global__ void k_bn1_stats(const float* __restrict__ feat, float* __restrict__ pacc) {
  float s[6] = {0,0,0,0,0,0}, q[6] = {0,0,0,0,0,0};
  int idx = blockIdx.x * blockDim.x + threadIdx.x;
  int stride = gridDim.x * blockDim.x;
  for (int r2 = idx; r2 < cN0 / 2; r2 += stride) {
    const float4* p = (const float4*)(feat + (size_t)r2 * 12);
    float4 a = p[0], b = p[1], c = p[2];
    s[0] += a.x + b.z;  q[0] += a.x*a.x + b.z*b.z;
    s[1] += a.y + b.w;  q[1] += a.y*a.y + b.w*b.w;
    s[2] += a.z + c.x;  q[2] += a.z*a.z + c.x*c.x;
    s[3] += a.w + c.y;  q[3] += a.w*a.w + c.y*c.y;
    s[4] += b.x + c.z;  q[4] += b.x*b.x + c.z*c.z;
    s[5] += b.y + c.w;  q[5] += b.y*b.y + c.w*c.w;
  }
#pragma unroll
  for (int k = 0; k < 6; k++) {
    for (int off = 32; off; off >>= 1) {
      s[k] += __shfl_down(s[k], off, 64);
      q[k] += __shfl_down(q[k], off, 64);
    }
  }
  __shared__ float ls[4][12];
  int wid = threadIdx.x >> 6;
  if ((threadIdx.x & 63) == 0) {
#pragma unroll
    for (int k = 0; k < 6; k++) { ls[wid][k] = s[k]; ls[wid][6 + k] = q[k]; }
  }
  __syncthreads();
  if (threadIdx.x < 12) {
    pacc[blockIdx.x * 12 + threadIdx.x] =
        ls[0][threadIdx.x] + ls[1][threadIdx.x] + ls[2][threadIdx.x] + ls[3][threadIdx.x];
  }
}

// ---------------- finalize per-channel scale/shift from npart block partials ----------------
__global__ void k_finalize(const float* __restrict__ pacc, int npart,
                           const float* __restrict__ g, const float* __restrict__ b,
                           float* __restrict__ ss, int ncols, float inv_n) {
  int c = threadIdx.x;
  if (c >= ncols) return;
  float s = 0.f, q = 0.f;
  for (int p = 0; p < npart; p++) {
    s += pacc[p * 2 * ncols + c];
    q += pacc[p * 2 * ncols + ncols + c];
  }
  float m = s * inv_n;
  float v = q * inv_n - m * m;
  float sc = g[c] * rsqrtf(v + 1e-5f);
  ss[c] = sc;
  ss[ncols + c] = b[c] - m * sc;
}

// ---------------- embedding: t = bn1(feat) @ W_emb  (6 -> 80) ----------------
__global__ void k_emb4(const float* __restrict__ feat, const float* __restrict__ Wemb,
                       const float* __restrict__ ss, float* __restrict__ t) {
  __shared__ float Wl[6 * HID];
  __shared__ float sc[12];
  for (int i = threadIdx.x; i < 6 * HID; i += blockDim.x) Wl[i] = Wemb[i];
  if (threadIdx.x < 12) sc[threadIdx.x] = ss[threadIdx.x];
  __syncthreads();
  int gid = blockIdx.x * blockDim.x + threadIdx.x;
  if (gid >= cN0 * (HID/4)) return;
  int r = gid / (HID/4);
  int c4 = (gid - r * (HID/4)) * 4;
  float a[6];
#pragma unroll
  for (int k = 0; k < 6; k++) a[k] = feat[r*6 + k] * sc[k] + sc[6 + k];
  float4 o;
  float* op = (float*)&o;
#pragma unroll
  for (int i = 0; i < 4; i++) {
    float v = 0.f;
#pragma unroll
    for (int k = 0; k < 6; k++) v += a[k] * Wl[k*HID + c4 + i];
    op[i] = v;
  }
  *(float4*)(t + (size_t)r*HID + c4) = o;
}

// ---------------- column stats -> per-block partials (LDS atomics only) ----------------
__global__ void k_colstats(const float* __restrict__ x, int nrows, int ncols,
                           float* __restrict__ pacc) {
  extern __shared__ float ls[]; // 2*ncols
  int c = threadIdx.x % ncols;
  int sub = threadIdx.x / ncols;
  int rows_per = blockDim.x / ncols;
  for (int i = threadIdx.x; i < 2*ncols; i += blockDim.x) ls[i] = 0.f;
  __syncthreads();
  float s = 0.f, q = 0.f;
  for (int r = blockIdx.x * rows_per + sub; r < nrows; r += gridDim.x * rows_per) {
    float v = x[(size_t)r * ncols + c];
    s += v; q += v*v;
  }
  atomicAdd(&ls[c], s);
  atomicAdd(&ls[ncols + c], q);
  __syncthreads();
  for (int i = threadIdx.x; i < 2*ncols; i += blockDim.x)
    pacc[blockIdx.x * 2 * ncols + i] = ls[i];
}

// ---------------- in-place scale+shift+relu over 80-col matrix ----------------
__global__ void k_scale_relu4(float* __restrict__ x, const float* __restrict__ ss, int ntot4) {
  int gid = blockIdx.x * blockDim.x + threadIdx.x;
  if (gid >= ntot4) return;
  int r = gid / (HID/4);
  int c4 = (gid - r * (HID/4)) * 4;
  float4 t = *(float4*)(x + (size_t)r*HID + c4);
  float* tp = (float*)&t;
#pragma unroll
  for (int i = 0; i < 4; i++) {
    float v = tp[i] * ss[c4 + i] + ss[HID + c4 + i];
    tp[i] = v > 0.f ? v : 0.f;
  }
  *(float4*)(x + (size_t)r*HID + c4) = t;
}

// ---------------- binned CSR build (deterministic, atomic-free scatter) ----------------
// Bins: 1024 dst nodes each. Level bin counts {128,64,32,16} -> 240 bins total.
#define NBINS 240
#define NEDGE_TOT 1720320
#define BIN_CHUNK 2048   // edges per WG; 1720320/2048 = 840 WGs, level-exact splits
#define NWG 840

struct BinP {
  const int* ii[4]; const int* jj[4];
  int* hist;    // [NWG][NBINS] per-WG bin histograms
  int* offs;    // [NBINS][NWG] exclusive WG-prefix within bin
  int* total;   // [NBINS]
  int* base;    // [NBINS+1] exclusive scan of totals
  int* pairs;   // [NEDGE_TOT] packed (i_local<<17 | j), bin-grouped
  int* rp[4]; int* col[4];
};

__device__ __forceinline__ int edge_level(int gid, int& el) {
  if (gid < 917504)  { el = gid;           return 0; }
  if (gid < 1376256) { el = gid - 917504;  return 1; }
  if (gid < 1605632) { el = gid - 1376256; return 2; }
  el = gid - 1605632; return 3;
}
__device__ __forceinline__ int blk_level(int b, int& lb) {
  if (b < 128) { lb = b;       return 0; }
  if (b < 192) { lb = b - 128; return 1; }
  if (b < 224) { lb = b - 192; return 2; }
  lb = b - 224; return 3;
}
__constant__ const int cNN[4] = {131072, 65536, 32768, 16384};
__constant__ const int cNE[4] = {917504, 458752, 229376, 114688};
__constant__ const int cNB[4] = {128, 64, 32, 16};
__constant__ const int cLB[4] = {0, 128, 192, 224};   // first bin of each level

// Pass A: per-WG LDS histogram over 240 bins -> hist[wg][b] (coalesced write).
__global__ void k_binA(BinP p) {
  __shared__ int h[NBINS];
  for (int i = threadIdx.x; i < NBINS; i += 256) h[i] = 0;
  __syncthreads();
  int ebase = blockIdx.x * BIN_CHUNK;
#pragma unroll
  for (int it = 0; it < BIN_CHUNK / 256; it++) {
    int e = ebase + it * 256 + threadIdx.x;
    int el; int l = edge_level(e, el);
    atomicAdd(&h[cLB[l] + (p.ii[l][el] >> 10)], 1);
  }
  __syncthreads();
  for (int b = threadIdx.x; b < NBINS; b += 256)
    p.hist[blockIdx.x * NBINS + b] = h[b];
}

// Pass T: one WG per bin. Exclusive scan of hist[:,b] over the 840 WGs.
__global__ void k_binT(BinP p) {
  __shared__ int sd[256];
  int b = blockIdx.x;
  int t = threadIdx.x;
  int carry = 0;
  for (int r = 0; r < 4; r++) {
    int idx = r * 256 + t;
    int v = (idx < NWG) ? p.hist[idx * NBINS + b] : 0;
    sd[t] = v;
    __syncthreads();
    for (int off = 1; off < 256; off <<= 1) {
      int x = sd[t];
      if (t >= off) x += sd[t - off];
      __syncthreads();
      sd[t] = x;
      __syncthreads();
    }
    if (idx < NWG) p.offs[b * NWG + idx] = carry + sd[t] - v;  // exclusive
    carry += sd[255];
    __syncthreads();
  }
  if (t == 0) p.total[b] = carry;
}

// Pass S: 1 WG, exclusive scan of 240 bin totals -> base[241].
__global__ void k_binScan2(BinP p) {
  __shared__ int sd[256];
  int t = threadIdx.x;
  int v = (t < NBINS) ? p.total[t] : 0;
  sd[t] = v;
  __syncthreads();
  for (int off = 1; off < 256; off <<= 1) {
    int x = sd[t];
    if (t >= off) x += sd[t - off];
    __syncthreads();
    sd[t] = x;
    __syncthreads();
  }
  if (t < NBINS) p.base[t] = sd[t] - v;
  if (t == NBINS - 1) p.base[NBINS] = sd[t];
}

// Pass B: deterministic scatter. LDS cursors seeded with base[b]+offs[b][wg];
// per-edge LDS atomicAdd + plain global store. Each (bin,wg) mini-segment
// (~1 line) is written by exactly one WG -> lines merge in L2.
__global__ void k_binB(BinP p) {
  __shared__ int cur[NBINS];
  int wg = blockIdx.x;
  for (int b = threadIdx.x; b < NBINS; b += 256)
    cur[b] = p.base[b] + p.offs[b * NWG + wg];
  __syncthreads();
  int ebase = wg * BIN_CHUNK;
#pragma unroll
  for (int it = 0; it < BIN_CHUNK / 256; it++) {
    int e = ebase + it * 256 + threadIdx.x;
    int el; int l = edge_level(e, el);
    int i = p.ii[l][el], j = p.jj[l][el];
    int b = cLB[l] + (i >> 10);
    int gpos = atomicAdd(&cur[b], 1);
    p.pairs[gpos] = ((i & 1023) << 17) | j;   // j < 131072 -> 17 bits
  }
}

// Pass D: one WG per bin. LDS degree count + scan -> rp (coalesced int4),
// LDS cursors -> col scatter confined to this bin's contiguous ~28KB region.
__global__ void __launch_bounds__(256) k_binCSR(BinP p) {
  __shared__ int d[1024];
  __shared__ int sd[256];
  int lb; int l = blk_level(blockIdx.x, lb);
  int t = threadIdx.x;
  int e0g = p.base[blockIdx.x];
  int e1g = p.base[blockIdx.x + 1];
  int lvlbase = p.base[cLB[l]];
  int e0 = e0g - lvlbase;               // level-local edge base of this bin
  for (int i = t; i < 1024; i += 256) d[i] = 0;
  __syncthreads();
  for (int e = e0g + t; e < e1g; e += 256)
    atomicAdd(&d[p.pairs[e] >> 17], 1);
  __syncthreads();
  int a0 = d[4*t], a1 = d[4*t+1], a2 = d[4*t+2], a3 = d[4*t+3];
  int ts = a0 + a1 + a2 + a3;
  sd[t] = ts;
  __syncthreads();
  for (int off = 1; off < 256; off <<= 1) {
    int x = sd[t];
    if (t >= off) x += sd[t - off];
    __syncthreads();
    sd[t] = x;
    __syncthreads();
  }
  int c0 = e0 + sd[t] - ts;             // level-local exclusive prefix
  int c1 = c0 + a0, c2 = c1 + a1, c3 = c2 + a2;
  int* rp = p.rp[l];
  *(int4*)(rp + lb * 1024 + 4 * t) = make_int4(c0, c1, c2, c3);
  if (t == 0 && lb == cNB[l] - 1) rp[cNN[l]] = cNE[l];
  d[4*t] = c0; d[4*t+1] = c1; d[4*t+2] = c2; d[4*t+3] = c3;   // cursors
  __syncthreads();
  int* col = p.col[l];
  for (int e = e0g + t; e < e1g; e += 256) {
    int pk = p.pairs[e];
    int slot = atomicAdd(&d[pk >> 17], 1);
    col[slot] = pk & 0x1FFFF;
  }
}

// ---------------- GEMM: out = act(in @ W + bias), 2 rows x 16 cols per thread ----------------
// R6 structure (W wave-uniform s_load, ~40 VGPR), R7 grid-axis swap:
// blockIdx.x = col group (fast in dispatch order), blockIdx.y = row block ->
// the KOUT/16 blocks sharing a 512-row slice dispatch back-to-back and hit
// L2/L3 on passes 2..5 instead of re-fetching from HBM.
// grid = (KOUT/16, half/256).
template <int KIN, int KOUT, bool ELU>
__global__ void __launch_bounds__(256) k_gemm(const float* __restrict__ in,
                                              const float* __restrict__ W,
                                              const float* __restrict__ bias,
                                              float* __restrict__ out, int half) {
  int r = blockIdx.y * 256 + threadIdx.x;
  int c0 = blockIdx.x * 16;
  float acc0[16], acc1[16];
#pragma unroll
  for (int i = 0; i < 16; i++) {
    float bv = bias ? bias[c0 + i] : 0.f;
    acc0[i] = bv; acc1[i] = bv;
  }
  const float* rowA = in + (size_t)r * KIN;
  const float* rowB = in + ((size_t)r + half) * KIN;
  for (int k = 0; k < KIN; k += 4) {
    float4 a = *(const float4*)(rowA + k);
    float4 b = *(const float4*)(rowB + k);
    const float* wk = W + (size_t)k * KOUT + c0;   // wave-uniform
#pragma unroll
    for (int i = 0; i < 16; i++) {
      float w0 = wk[i], w1 = wk[KOUT + i], w2 = wk[2*KOUT + i], w3 = wk[3*KOUT + i];
      acc0[i] += a.x * w0 + a.y * w1 + a.z * w2 + a.w * w3;
      acc1[i] += b.x * w0 + b.y * w1 + b.z * w2 + b.w * w3;
    }
  }
  float* orowA = out + (size_t)r * KOUT + c0;
  float* orowB = out + ((size_t)r + half) * KOUT + c0;
#pragma unroll
  for (int u = 0; u < 4; u++) {
    float a0 = acc0[4*u+0], a1 = acc0[4*u+1], a2 = acc0[4*u+2], a3 = acc0[4*u+3];
    float b0 = acc1[4*u+0], b1 = acc1[4*u+1], b2 = acc1[4*u+2], b3 = acc1[4*u+3];
    if (ELU) {
      a0 = a0 > 0.f ? a0 : expm1f(a0);  a1 = a1 > 0.f ? a1 : expm1f(a1);
      a2 = a2 > 0.f ? a2 : expm1f(a2);  a3 = a3 > 0.f ? a3 : expm1f(a3);
      b0 = b0 > 0.f ? b0 : expm1f(b0);  b1 = b1 > 0.f ? b1 : expm1f(b1);
      b2 = b2 > 0.f ? b2 : expm1f(b2);  b3 = b3 > 0.f ? b3 : expm1f(b3);
    }
    float4 oa; oa.x = a0; oa.y = a1; oa.z = a2; oa.w = a3;
    float4 ob; ob.x = b0; ob.y = b1; ob.z = b2; ob.w = b3;
    *(float4*)(orowA + 4*u) = oa;
    *(float4*)(orowB + 4*u) = ob;
  }
}

// ---------------- f = elu(h + CSR-gather-sum(hW)), float4 per thread ----------------
__global__ void k_agg_elu4(const float* __restrict__ h, const float* __restrict__ hW,
                           const int* __restrict__ rp, const int* __restrict__ col,
                           float* __restrict__ f, int n) {
  int gid = blockIdx.x * blockDim.x + threadIdx.x;
  if (gid >= n * (HID/4)) return;
  int v = gid / (HID/4);
  int c4 = (gid - v * (HID/4)) * 4;
  int e0 = rp[v], e1 = rp[v + 1];
  float4 s = *(const float4*)(h + (size_t)v*HID + c4);
  float* sp = (float*)&s;
  for (int e = e0; e < e1; e++) {
    int j = col[e];
    float4 x = *(const float4*)(hW + (size_t)j*HID + c4);
    sp[0] += x.x; sp[1] += x.y; sp[2] += x.z; sp[3] += x.w;
  }
#pragma unroll
  for (int i = 0; i < 4; i++) sp[i] = eluf(sp[i]);
  *(float4*)(f + (size_t)v*HID + c4) = s;
}

// ---------------- dst[v] = sum over CSR of src[j], src = (j<half ? top : old) ----------------
__global__ void k_prop4(const float* __restrict__ top, const float* __restrict__ oldb,
                        int half, const int* __restrict__ rp, const int* __restrict__ col,
                        float* __restrict__ dst, int n) {
  int gid = blockIdx.x * blockDim.x + threadIdx.x;
  if (gid >= n * (HID/4)) return;
  int v = gid / (HID/4);
  int c4 = (gid - v * (HID/4)) * 4;
  int e0 = rp[v], e1 = rp[v + 1];
  float4 s = {0,0,0,0};
  float* sp = (float*)&s;
  for (int e = e0; e < e1; e++) {
    int j = col[e];
    const float* src = (j < half) ? top : oldb;
    float4 x = *(const float4*)(src + (size_t)j*HID + c4);
    sp[0] += x.x; sp[1] += x.y; sp[2] += x.z; sp[3] += x.w;
  }
  *(float4*)(dst + (size_t)v*HID + c4) = s;
}

// ---------------- finalize bn2 (from partials) and fold into Wc ----------------
__global__ void k_fin_bn2(const float* __restrict__ pacc, int npart,
                          const float* __restrict__ g, const float* __restrict__ b,
                          const float* __restrict__ Wc, float* __restrict__ wcp) {
  __shared__ float sc[64], sh[64];
  int t = threadIdx.x; // 64 threads
  float s = 0.f, q = 0.f;
  for (int p = 0; p < npart; p++) {
    s += pacc[p * 128 + t];
    q += pacc[p * 128 + 64 + t];
  }
  float invn = 1.f / (float)cN0;
  float m = s * invn;
  float v = q * invn - m * m;
  float scv = g[t] * rsqrtf(v + 1e-5f);
  sc[t] = scv;
  sh[t] = b[t] - m * scv;
  __syncthreads();
  for (int i = t; i < 64 * 13; i += 64) { int c = i / 13; wcp[i] = sc[c] * Wc[i]; }
  if (t < 13) {
    float acc13 = 0.f;
    for (int c = 0; c < 64; c++) acc13 += sh[c] * Wc[c*13 + t];
    wcp[64*13 + t] = acc13;
  }
}

// ---------------- final: out = bn2(x3) @ Wc  == x3 @ Wc' + bias13 ----------------
__global__ void k_final(const float* __restrict__ x3, const float* __restrict__ wcp,
                        float* __restrict__ out) {
  __shared__ float Wl[64*13 + 13];
  for (int i = threadIdx.x; i < 64*13 + 13; i += blockDim.x) Wl[i] = wcp[i];
  __syncthreads();
  int gid = blockIdx.x * blockDim.x + threadIdx.x; // exactly N0*13
  int r = gid / 13, o = gid - r * 13;
  const float* row = x3 + (size_t)r * 64;
  float s = Wl[64*13 + o];
#pragma unroll
  for (int c = 0; c < 64; c++) s += row[c] * Wl[c*13 + o];
  out[gid] = s;
}

// ===========================================================================
extern "C" void kernel_launch(void* const* d_in, const int* in_sizes, int n_in,
                              void* d_out, int out_size, void* d_ws, size_t ws_size,
                              hipStream_t stream) {
  const float* feat   = (const float*)d_in[0];
  const float* bn1_g  = (const float*)d_in[1];
  const float* bn1_b  = (const float*)d_in[2];
  const float* W_emb  = (const float*)d_in[3];
  const float* embn_g = (const float*)d_in[4];
  const float* embn_b = (const float*)d_in[5];
  const float* W_msg  = (const float*)d_in[6];
  const float* W1 = (const float*)d_in[7];
  const float* b1 = (const float*)d_in[8];
  const float* W2 = (const float*)d_in[9];
  const float* b2 = (const float*)d_in[10];
  const float* W3 = (const float*)d_in[11];
  const float* b3 = (const float*)d_in[12];
  const float* bn2_g = (const float*)d_in[13];
  const float* bn2_b = (const float*)d_in[14];
  const float* Wc    = (const float*)d_in[15];

  const int NNODE[4] = {131072, 65536, 32768, 16384};
  const int NEDGE[4] = {917504, 458752, 229376, 114688};
  const int N = cN0;
  const int SBLK = 256;   // colstats partial blocks
  const int BN1B = 64;    // bn1 partial blocks

  // ---- workspace arena (256B-aligned) ----
  size_t off = 0;
  char* base = (char*)d_ws;
  auto af = [&](size_t nf) -> float* { float* p = (float*)(base + off); off += ((nf*4 + 255) & ~(size_t)255); return p; };
  auto ai = [&](size_t ni) -> int*   { int*   p = (int*)  (base + off); off += ((ni*4 + 255) & ~(size_t)255); return p; };

  int* hist   = ai((size_t)NWG * NBINS);
  int* offs   = ai((size_t)NBINS * NWG);
  int* total  = ai(NBINS);
  int* bbase  = ai(NBINS + 1);
  int* pairs  = ai(NEDGE_TOT);

  float* pacc1 = af((size_t)BN1B * 12);
  float* pacce = af((size_t)SBLK * 160);
  float* pacc2 = af((size_t)SBLK * 128);
  float* ss1 = af(12);
  float* sse = af(160);
  float* wcp = af(64*13 + 13);
  int* rp[4];   for (int l = 0; l < 4; l++) rp[l]   = ai(NNODE[l] + 1);
  int* col[4];  for (int l = 0; l < 4; l++) col[l]  = ai(NEDGE[l]);

  float* t_h0 = af((size_t)N * HID);     // t -> h0 in place; later hud0 ping (H0P)
  float* hWb  = af((size_t)N * HID);     // hW per level; later hud0 pong (H0Q)
  float* f[4];
  f[0] = af((size_t)NNODE[0] * HID);
  f[1] = af((size_t)NNODE[1] * HID);
  f[2] = af((size_t)NNODE[2] * HID);
  f[3] = af((size_t)NNODE[3] * HID);
  float* h1a = af((size_t)NNODE[1] * HID);
  float* h1b = af((size_t)NNODE[1] * HID);
  float* h2a = af((size_t)NNODE[2] * HID);
  float* h2b = af((size_t)NNODE[2] * HID);
  float* h3  = af((size_t)NNODE[3] * HID);

  float* x1 = f[0];           // N*64 fits in f0's N*80
  float* x2 = f[1];           // N*64 fits in f1+f2+f3 span
  float* x3 = f[0];
  (void)ws_size; (void)in_sizes; (void)n_in; (void)out_size;

  // ---- bn1 -> scale/shift; embed; embn -> scale/shift; relu ----
  k_bn1_stats<<<BN1B, 256, 0, stream>>>(feat, pacc1);
  k_finalize<<<1, 64, 0, stream>>>(pacc1, BN1B, bn1_g, bn1_b, ss1, 6, 1.f / N);
  k_emb4<<<(N * (HID/4)) / 256, 256, 0, stream>>>(feat, W_emb, ss1, t_h0);
  k_colstats<<<SBLK, 320, 2*80*4, stream>>>(t_h0, N, 80, pacce);
  k_finalize<<<1, 128, 0, stream>>>(pacce, SBLK, embn_g, embn_b, sse, 80, 1.f / N);
  k_scale_relu4<<<(N * (HID/4)) / 256, 256, 0, stream>>>(t_h0, sse, N * (HID/4));

  // ---- binned CSR build, deterministic: 5 launches, no global atomics ----
  BinP bp;
  for (int l = 0; l < 4; l++) {
    bp.ii[l] = (const int*)d_in[16 + 2*l];
    bp.jj[l] = (const int*)d_in[17 + 2*l];
    bp.rp[l] = rp[l]; bp.col[l] = col[l];
  }
  bp.hist = hist; bp.offs = offs; bp.total = total; bp.base = bbase; bp.pairs = pairs;
  k_binA<<<NWG, 256, 0, stream>>>(bp);
  k_binT<<<NBINS, 256, 0, stream>>>(bp);
  k_binScan2<<<1, 256, 0, stream>>>(bp);
  k_binB<<<NWG, 256, 0, stream>>>(bp);
  k_binCSR<<<NBINS, 256, 0, stream>>>(bp);

  // ---- features per level: hW = h @ W_msg[l]; f = elu(h + csr_sum(hW)) ----
  const float* hin = t_h0;
  for (int l = 0; l < 4; l++) {
    int n = NNODE[l];
    dim3 g(HID / 16, n / 512);
    k_gemm<80, 80, false><<<g, 256, 0, stream>>>(hin, W_msg + (size_t)l * HID * HID, nullptr, hWb, n / 2);
    k_agg_elu4<<<(n * (HID/4)) / 256, 256, 0, stream>>>(hin, hWb, rp[l], col[l], f[l], n);
    hin = f[l];
  }

  // ---- propagation: 10 unrolled segment-sums with conditional-source mix ----
  float* H0P = t_h0;  // h0 dead after features phase
  float* H0Q = hWb;   // hW dead after features phase
  const int B = 256;
  // l=0
  k_prop4<<<(NNODE[0]*(HID/4))/B, B, 0, stream>>>(f[0], f[0], NNODE[0], rp[0], col[0], H0P, NNODE[0]);
  // l=1
  k_prop4<<<(NNODE[1]*(HID/4))/B, B, 0, stream>>>(f[1], f[1], NNODE[1], rp[1], col[1], h1a, NNODE[1]);
  k_prop4<<<(NNODE[0]*(HID/4))/B, B, 0, stream>>>(h1a, H0P, 65536, rp[0], col[0], H0Q, NNODE[0]);
  // l=2
  k_prop4<<<(NNODE[2]*(HID/4))/B, B, 0, stream>>>(f[2], f[2], NNODE[2], rp[2], col[2], h2a, NNODE[2]);
  k_prop4<<<(NNODE[1]*(HID/4))/B, B, 0, stream>>>(h2a, h1a, 32768, rp[1], col[1], h1b, NNODE[1]);
  k_prop4<<<(NNODE[0]*(HID/4))/B, B, 0, stream>>>(h1b, H0Q, 65536, rp[0], col[0], H0P, NNODE[0]);
  // l=3
  k_prop4<<<(NNODE[3]*(HID/4))/B, B, 0, stream>>>(f[3], f[3], NNODE[3], rp[3], col[3], h3, NNODE[3]);
  k_prop4<<<(NNODE[2]*(HID/4))/B, B, 0, stream>>>(h3, h2a, 16384, rp[2], col[2], h2b, NNODE[2]);
  k_prop4<<<(NNODE[1]*(HID/4))/B, B, 0, stream>>>(h2b, h1b, 32768, rp[1], col[1], h1a, NNODE[1]);
  k_prop4<<<(NNODE[0]*(HID/4))/B, B, 0, stream>>>(h1a, H0P, 65536, rp[0], col[0], H0Q, NNODE[0]);
  // final h_up_down == H0Q

  // ---- MLP head + bn2 folded into Wc ----
  k_gemm<80, 64, true><<<dim3(4, N/512), 256, 0, stream>>>(H0Q, W1, b1, x1, N/2);
  k_gemm<64, 64, true><<<dim3(4, N/512), 256, 0, stream>>>(x1, W2, b2, x2, N/2);
  k_gemm<64, 64, true><<<dim3(4, N/512), 256, 0, stream>>>(x2, W3, b3, x3, N/2);
  k_colstats<<<SBLK, 256, 2*64*4, stream>>>(x3, N, 64, pacc2);
  k_fin_bn2<<<1, 64, 0, stream>>>(pacc2, SBLK, bn2_g, bn2_b, Wc, wcp);
  k_final<<<(N * 13) / 256, 256, 0, stream>>>(x3, wcp, (float*)d_out);
}

// Round 7
// 1020.737 us; speedup vs baseline: 1.5662x; 1.5662x over previous
//
#include <hip/hip_runtime.h>
#include <math.h>

// ---------------------------------------------------------------------------
// FancyNet: 4-level hierarchical GNN + MLP head on MI355X.
//   * hW = h @ W_msg per-node (gather commutes with matmul) -> 7x less GEMM
//   * up_l == arange(N_l/2) => downsample = first-half rows; ".at[up].set(hud)"
//     = conditional-source read (j<half ? top : old)
//   * propagation unrolled to 10 prop kernels with ping-pong buffers
//   * BN folds to scale/shift; bn2 folded into Wc' + bias13
//   * R1 fix: NO contended global float atomics (stats via block partials).
//   * R3 fix: deterministic two-level counting-sort CSR build.
//   * R4/R5 lesson: full-row-in-registers GEMM spills to scratch. Rule #20.
//   * R6: 2-rows/thread gemm, col groups via blockIdx.y. 1136us; FETCH 124MB
//     (3x re-read of the input across 5 col passes).
//   * R7 lesson: making col groups fast-varying put the 5 blocks sharing a
//     row slice on 5 DIFFERENT XCDs (round-robin dispatch, private L2s) ->
//     FETCH 685MB, 207us. Dispatch-order tuning can't fix multi-pass reads.
//   * R8: one-pass gemm. Block = 64 rows x ALL cols. A-tile TRANSPOSED in
//     LDS (As[k][64]: conflict-free per-k wave reads, coalesced staging).
//     W via wave-uniform scalar loads (c0 = readfirstlane((tid>>6)*CPT) ->
//     s_load, R6's proven mechanism). Vector pipe: 1 ds_read + CPT FMA per
//     k -> FMA-bound. acc[CPT] statically indexed, ~40 VGPR, no spill risk.
// ---------------------------------------------------------------------------

#define HID 80
constexpr int cN0 = 131072;

__device__ __forceinline__ float eluf(float x) { return x > 0.f ? x : expm1f(x); }

// ---------------- bn1 stats (6 cols): 2 rows/thread as 3x float4, block partials ----------------
__global__ void k_bn1_stats(const float* __restrict__ feat, float* __restrict__ pacc) {
  float s[6] = {0,0,0,0,0,0}, q[6] = {0,0,0,0,0,0};
  int idx = blockIdx.x * blockDim.x + threadIdx.x;
  int stride = gridDim.x * blockDim.x;
  for (int r2 = idx; r2 < cN0 / 2; r2 += stride) {
    const float4* p = (const float4*)(feat + (size_t)r2 * 12);
    float4 a = p[0], b = p[1], c = p[2];
    s[0] += a.x + b.z;  q[0] += a.x*a.x + b.z*b.z;
    s[1] += a.y + b.w;  q[1] += a.y*a.y + b.w*b.w;
    s[2] += a.z + c.x;  q[2] += a.z*a.z + c.x*c.x;
    s[3] += a.w + c.y;  q[3] += a.w*a.w + c.y*c.y;
    s[4] += b.x + c.z;  q[4] += b.x*b.x + c.z*c.z;
    s[5] += b.y + c.w;  q[5] += b.y*b.y + c.w*c.w;
  }
#pragma unroll
  for (int k = 0; k < 6; k++) {
    for (int off = 32; off; off >>= 1) {
      s[k] += __shfl_down(s[k], off, 64);
      q[k] += __shfl_down(q[k], off, 64);
    }
  }
  __shared__ float ls[4][12];
  int wid = threadIdx.x >> 6;
  if ((threadIdx.x & 63) == 0) {
#pragma unroll
    for (int k = 0; k < 6; k++) { ls[wid][k] = s[k]; ls[wid][6 + k] = q[k]; }
  }
  __syncthreads();
  if (threadIdx.x < 12) {
    pacc[blockIdx.x * 12 + threadIdx.x] =
        ls[0][threadIdx.x] + ls[1][threadIdx.x] + ls[2][threadIdx.x] + ls[3][threadIdx.x];
  }
}

// ---------------- finalize per-channel scale/shift from npart block partials ----------------
__global__ void k_finalize(const float* __restrict__ pacc, int npart,
                           const float* __restrict__ g, const float* __restrict__ b,
                           float* __restrict__ ss, int ncols, float inv_n) {
  int c = threadIdx.x;
  if (c >= ncols) return;
  float s = 0.f, q = 0.f;
  for (int p = 0; p < npart; p++) {
    s += pacc[p * 2 * ncols + c];
    q += pacc[p * 2 * ncols + ncols + c];
  }
  float m = s * inv_n;
  float v = q * inv_n - m * m;
  float sc = g[c] * rsqrtf(v + 1e-5f);
  ss[c] = sc;
  ss[ncols + c] = b[c] - m * sc;
}

// ---------------- embedding: t = bn1(feat) @ W_emb  (6 -> 80) ----------------
__global__ void k_emb4(const float* __restrict__ feat, const float* __restrict__ Wemb,
                       const float* __restrict__ ss, float* __restrict__ t) {
  __shared__ float Wl[6 * HID];
  __shared__ float sc[12];
  for (int i = threadIdx.x; i < 6 * HID; i += blockDim.x) Wl[i] = Wemb[i];
  if (threadIdx.x < 12) sc[threadIdx.x] = ss[threadIdx.x];
  __syncthreads();
  int gid = blockIdx.x * blockDim.x + threadIdx.x;
  if (gid >= cN0 * (HID/4)) return;
  int r = gid / (HID/4);
  int c4 = (gid - r * (HID/4)) * 4;
  float a[6];
#pragma unroll
  for (int k = 0; k < 6; k++) a[k] = feat[r*6 + k] * sc[k] + sc[6 + k];
  float4 o;
  float* op = (float*)&o;
#pragma unroll
  for (int i = 0; i < 4; i++) {
    float v = 0.f;
#pragma unroll
    for (int k = 0; k < 6; k++) v += a[k] * Wl[k*HID + c4 + i];
    op[i] = v;
  }
  *(float4*)(t + (size_t)r*HID + c4) = o;
}

// ---------------- column stats -> per-block partials (LDS atomics only) ----------------
__global__ void k_colstats(const float* __restrict__ x, int nrows, int ncols,
                           float* __restrict__ pacc) {
  extern __shared__ float ls[]; // 2*ncols
  int c = threadIdx.x % ncols;
  int sub = threadIdx.x / ncols;
  int rows_per = blockDim.x / ncols;
  for (int i = threadIdx.x; i < 2*ncols; i += blockDim.x) ls[i] = 0.f;
  __syncthreads();
  float s = 0.f, q = 0.f;
  for (int r = blockIdx.x * rows_per + sub; r < nrows; r += gridDim.x * rows_per) {
    float v = x[(size_t)r * ncols + c];
    s += v; q += v*v;
  }
  atomicAdd(&ls[c], s);
  atomicAdd(&ls[ncols + c], q);
  __syncthreads();
  for (int i = threadIdx.x; i < 2*ncols; i += blockDim.x)
    pacc[blockIdx.x * 2 * ncols + i] = ls[i];
}

// ---------------- in-place scale+shift+relu over 80-col matrix ----------------
__global__ void k_scale_relu4(float* __restrict__ x, const float* __restrict__ ss, int ntot4) {
  int gid = blockIdx.x * blockDim.x + threadIdx.x;
  if (gid >= ntot4) return;
  int r = gid / (HID/4);
  int c4 = (gid - r * (HID/4)) * 4;
  float4 t = *(float4*)(x + (size_t)r*HID + c4);
  float* tp = (float*)&t;
#pragma unroll
  for (int i = 0; i < 4; i++) {
    float v = tp[i] * ss[c4 + i] + ss[HID + c4 + i];
    tp[i] = v > 0.f ? v : 0.f;
  }
  *(float4*)(x + (size_t)r*HID + c4) = t;
}

// ---------------- binned CSR build (deterministic, atomic-free scatter) ----------------
// Bins: 1024 dst nodes each. Level bin counts {128,64,32,16} -> 240 bins total.
#define NBINS 240
#define NEDGE_TOT 1720320
#define BIN_CHUNK 2048   // edges per WG; 1720320/2048 = 840 WGs, level-exact splits
#define NWG 840

struct BinP {
  const int* ii[4]; const int* jj[4];
  int* hist;    // [NWG][NBINS] per-WG bin histograms
  int* offs;    // [NBINS][NWG] exclusive WG-prefix within bin
  int* total;   // [NBINS]
  int* base;    // [NBINS+1] exclusive scan of totals
  int* pairs;   // [NEDGE_TOT] packed (i_local<<17 | j), bin-grouped
  int* rp[4]; int* col[4];
};

__device__ __forceinline__ int edge_level(int gid, int& el) {
  if (gid < 917504)  { el = gid;           return 0; }
  if (gid < 1376256) { el = gid - 917504;  return 1; }
  if (gid < 1605632) { el = gid - 1376256; return 2; }
  el = gid - 1605632; return 3;
}
__device__ __forceinline__ int blk_level(int b, int& lb) {
  if (b < 128) { lb = b;       return 0; }
  if (b < 192) { lb = b - 128; return 1; }
  if (b < 224) { lb = b - 192; return 2; }
  lb = b - 224; return 3;
}
__constant__ const int cNN[4] = {131072, 65536, 32768, 16384};
__constant__ const int cNE[4] = {917504, 458752, 229376, 114688};
__constant__ const int cNB[4] = {128, 64, 32, 16};
__constant__ const int cLB[4] = {0, 128, 192, 224};   // first bin of each level

// Pass A: per-WG LDS histogram over 240 bins -> hist[wg][b] (coalesced write).
__global__ void k_binA(BinP p) {
  __shared__ int h[NBINS];
  for (int i = threadIdx.x; i < NBINS; i += 256) h[i] = 0;
  __syncthreads();
  int ebase = blockIdx.x * BIN_CHUNK;
#pragma unroll
  for (int it = 0; it < BIN_CHUNK / 256; it++) {
    int e = ebase + it * 256 + threadIdx.x;
    int el; int l = edge_level(e, el);
    atomicAdd(&h[cLB[l] + (p.ii[l][el] >> 10)], 1);
  }
  __syncthreads();
  for (int b = threadIdx.x; b < NBINS; b += 256)
    p.hist[blockIdx.x * NBINS + b] = h[b];
}

// Pass T: one WG per bin. Exclusive scan of hist[:,b] over the 840 WGs.
__global__ void k_binT(BinP p) {
  __shared__ int sd[256];
  int b = blockIdx.x;
  int t = threadIdx.x;
  int carry = 0;
  for (int r = 0; r < 4; r++) {
    int idx = r * 256 + t;
    int v = (idx < NWG) ? p.hist[idx * NBINS + b] : 0;
    sd[t] = v;
    __syncthreads();
    for (int off = 1; off < 256; off <<= 1) {
      int x = sd[t];
      if (t >= off) x += sd[t - off];
      __syncthreads();
      sd[t] = x;
      __syncthreads();
    }
    if (idx < NWG) p.offs[b * NWG + idx] = carry + sd[t] - v;  // exclusive
    carry += sd[255];
    __syncthreads();
  }
  if (t == 0) p.total[b] = carry;
}

// Pass S: 1 WG, exclusive scan of 240 bin totals -> base[241].
__global__ void k_binScan2(BinP p) {
  __shared__ int sd[256];
  int t = threadIdx.x;
  int v = (t < NBINS) ? p.total[t] : 0;
  sd[t] = v;
  __syncthreads();
  for (int off = 1; off < 256; off <<= 1) {
    int x = sd[t];
    if (t >= off) x += sd[t - off];
    __syncthreads();
    sd[t] = x;
    __syncthreads();
  }
  if (t < NBINS) p.base[t] = sd[t] - v;
  if (t == NBINS - 1) p.base[NBINS] = sd[t];
}

// Pass B: deterministic scatter. LDS cursors seeded with base[b]+offs[b][wg];
// per-edge LDS atomicAdd + plain global store. Each (bin,wg) mini-segment
// (~1 line) is written by exactly one WG -> lines merge in L2.
__global__ void k_binB(BinP p) {
  __shared__ int cur[NBINS];
  int wg = blockIdx.x;
  for (int b = threadIdx.x; b < NBINS; b += 256)
    cur[b] = p.base[b] + p.offs[b * NWG + wg];
  __syncthreads();
  int ebase = wg * BIN_CHUNK;
#pragma unroll
  for (int it = 0; it < BIN_CHUNK / 256; it++) {
    int e = ebase + it * 256 + threadIdx.x;
    int el; int l = edge_level(e, el);
    int i = p.ii[l][el], j = p.jj[l][el];
    int b = cLB[l] + (i >> 10);
    int gpos = atomicAdd(&cur[b], 1);
    p.pairs[gpos] = ((i & 1023) << 17) | j;   // j < 131072 -> 17 bits
  }
}

// Pass D: one WG per bin. LDS degree count + scan -> rp (coalesced int4),
// LDS cursors -> col scatter confined to this bin's contiguous ~28KB region.
__global__ void __launch_bounds__(256) k_binCSR(BinP p) {
  __shared__ int d[1024];
  __shared__ int sd[256];
  int lb; int l = blk_level(blockIdx.x, lb);
  int t = threadIdx.x;
  int e0g = p.base[blockIdx.x];
  int e1g = p.base[blockIdx.x + 1];
  int lvlbase = p.base[cLB[l]];
  int e0 = e0g - lvlbase;               // level-local edge base of this bin
  for (int i = t; i < 1024; i += 256) d[i] = 0;
  __syncthreads();
  for (int e = e0g + t; e < e1g; e += 256)
    atomicAdd(&d[p.pairs[e] >> 17], 1);
  __syncthreads();
  int a0 = d[4*t], a1 = d[4*t+1], a2 = d[4*t+2], a3 = d[4*t+3];
  int ts = a0 + a1 + a2 + a3;
  sd[t] = ts;
  __syncthreads();
  for (int off = 1; off < 256; off <<= 1) {
    int x = sd[t];
    if (t >= off) x += sd[t - off];
    __syncthreads();
    sd[t] = x;
    __syncthreads();
  }
  int c0 = e0 + sd[t] - ts;             // level-local exclusive prefix
  int c1 = c0 + a0, c2 = c1 + a1, c3 = c2 + a2;
  int* rp = p.rp[l];
  *(int4*)(rp + lb * 1024 + 4 * t) = make_int4(c0, c1, c2, c3);
  if (t == 0 && lb == cNB[l] - 1) rp[cNN[l]] = cNE[l];
  d[4*t] = c0; d[4*t+1] = c1; d[4*t+2] = c2; d[4*t+3] = c3;   // cursors
  __syncthreads();
  int* col = p.col[l];
  for (int e = e0g + t; e < e1g; e += 256) {
    int pk = p.pairs[e];
    int slot = atomicAdd(&d[pk >> 17], 1);
    col[slot] = pk & 0x1FFFF;
  }
}

// ---------------- GEMM: out = act(in @ W + bias), one-pass, A-tile in LDS ----------------
// Block = 64 rows x ALL KOUT cols; input read exactly once. A staged
// TRANSPOSED (As[k][64]): staging coalesced, per-k wave read = 64 consecutive
// floats (conflict-free). W read via wave-uniform scalar loads: c0 forced to
// SGPR with readfirstlane -> s_load (R6's proven cheap path). Vector pipe per
// k: 1 ds_read + CPT FMAs. acc[CPT] statically indexed (~40 VGPR, no spill).
template <int KIN, int KOUT, bool ELU>
__global__ void __launch_bounds__(256) k_gemm(const float* __restrict__ in,
                                              const float* __restrict__ W,
                                              const float* __restrict__ bias,
                                              float* __restrict__ out) {
  constexpr int CPT = KOUT / 4;          // cols per thread (4 waves cover KOUT)
  __shared__ float As[KIN * 64];
  int rbase = blockIdx.x * 64;
  // stage 64 rows x KIN, transposed into As[k][row]
  for (int idx = threadIdx.x; idx < 16 * KIN; idx += 256) {
    int r = idx / (KIN / 4);
    int q = idx - r * (KIN / 4);
    float4 v = *(const float4*)(in + (size_t)(rbase + r) * KIN + q * 4);
    As[(q * 4 + 0) * 64 + r] = v.x;
    As[(q * 4 + 1) * 64 + r] = v.y;
    As[(q * 4 + 2) * 64 + r] = v.z;
    As[(q * 4 + 3) * 64 + r] = v.w;
  }
  __syncthreads();
  int row = threadIdx.x & 63;
  int c0 = __builtin_amdgcn_readfirstlane((threadIdx.x >> 6) * CPT);
  float acc[CPT];
#pragma unroll
  for (int i = 0; i < CPT; i++) acc[i] = bias ? bias[c0 + i] : 0.f;
#pragma unroll 4
  for (int k = 0; k < KIN; k++) {
    float a = As[k * 64 + row];
    const float* wk = W + (size_t)k * KOUT + c0;   // uniform -> s_load
#pragma unroll
    for (int i = 0; i < CPT; i++) acc[i] += a * wk[i];
  }
  float* orow = out + (size_t)(rbase + row) * KOUT + c0;
#pragma unroll
  for (int u = 0; u < CPT / 4; u++) {
    float v0 = acc[4*u+0], v1 = acc[4*u+1], v2 = acc[4*u+2], v3 = acc[4*u+3];
    if (ELU) {
      v0 = v0 > 0.f ? v0 : expm1f(v0);  v1 = v1 > 0.f ? v1 : expm1f(v1);
      v2 = v2 > 0.f ? v2 : expm1f(v2);  v3 = v3 > 0.f ? v3 : expm1f(v3);
    }
    float4 o; o.x = v0; o.y = v1; o.z = v2; o.w = v3;
    *(float4*)(orow + 4 * u) = o;
  }
}

// ---------------- f = elu(h + CSR-gather-sum(hW)), float4 per thread ----------------
__global__ void k_agg_elu4(const float* __restrict__ h, const float* __restrict__ hW,
                           const int* __restrict__ rp, const int* __restrict__ col,
                           float* __restrict__ f, int n) {
  int gid = blockIdx.x * blockDim.x + threadIdx.x;
  if (gid >= n * (HID/4)) return;
  int v = gid / (HID/4);
  int c4 = (gid - v * (HID/4)) * 4;
  int e0 = rp[v], e1 = rp[v + 1];
  float4 s = *(const float4*)(h + (size_t)v*HID + c4);
  float* sp = (float*)&s;
  for (int e = e0; e < e1; e++) {
    int j = col[e];
    float4 x = *(const float4*)(hW + (size_t)j*HID + c4);
    sp[0] += x.x; sp[1] += x.y; sp[2] += x.z; sp[3] += x.w;
  }
#pragma unroll
  for (int i = 0; i < 4; i++) sp[i] = eluf(sp[i]);
  *(float4*)(f + (size_t)v*HID + c4) = s;
}

// ---------------- dst[v] = sum over CSR of src[j], src = (j<half ? top : old) ----------------
__global__ void k_prop4(const float* __restrict__ top, const float* __restrict__ oldb,
                        int half, const int* __restrict__ rp, const int* __restrict__ col,
                        float* __restrict__ dst, int n) {
  int gid = blockIdx.x * blockDim.x + threadIdx.x;
  if (gid >= n * (HID/4)) return;
  int v = gid / (HID/4);
  int c4 = (gid - v * (HID/4)) * 4;
  int e0 = rp[v], e1 = rp[v + 1];
  float4 s = {0,0,0,0};
  float* sp = (float*)&s;
  for (int e = e0; e < e1; e++) {
    int j = col[e];
    const float* src = (j < half) ? top : oldb;
    float4 x = *(const float4*)(src + (size_t)j*HID + c4);
    sp[0] += x.x; sp[1] += x.y; sp[2] += x.z; sp[3] += x.w;
  }
  *(float4*)(dst + (size_t)v*HID + c4) = s;
}

// ---------------- finalize bn2 (from partials) and fold into Wc ----------------
__global__ void k_fin_bn2(const float* __restrict__ pacc, int npart,
                          const float* __restrict__ g, const float* __restrict__ b,
                          const float* __restrict__ Wc, float* __restrict__ wcp) {
  __shared__ float sc[64], sh[64];
  int t = threadIdx.x; // 64 threads
  float s = 0.f, q = 0.f;
  for (int p = 0; p < npart; p++) {
    s += pacc[p * 128 + t];
    q += pacc[p * 128 + 64 + t];
  }
  float invn = 1.f / (float)cN0;
  float m = s * invn;
  float v = q * invn - m * m;
  float scv = g[t] * rsqrtf(v + 1e-5f);
  sc[t] = scv;
  sh[t] = b[t] - m * scv;
  __syncthreads();
  for (int i = t; i < 64 * 13; i += 64) { int c = i / 13; wcp[i] = sc[c] * Wc[i]; }
  if (t < 13) {
    float acc13 = 0.f;
    for (int c = 0; c < 64; c++) acc13 += sh[c] * Wc[c*13 + t];
    wcp[64*13 + t] = acc13;
  }
}

// ---------------- final: out = bn2(x3) @ Wc  == x3 @ Wc' + bias13 ----------------
__global__ void k_final(const float* __restrict__ x3, const float* __restrict__ wcp,
                        float* __restrict__ out) {
  __shared__ float Wl[64*13 + 13];
  for (int i = threadIdx.x; i < 64*13 + 13; i += blockDim.x) Wl[i] = wcp[i];
  __syncthreads();
  int gid = blockIdx.x * blockDim.x + threadIdx.x; // exactly N0*13
  int r = gid / 13, o = gid - r * 13;
  const float* row = x3 + (size_t)r * 64;
  float s = Wl[64*13 + o];
#pragma unroll
  for (int c = 0; c < 64; c++) s += row[c] * Wl[c*13 + o];
  out[gid] = s;
}

// ===========================================================================
extern "C" void kernel_launch(void* const* d_in, const int* in_sizes, int n_in,
                              void* d_out, int out_size, void* d_ws, size_t ws_size,
                              hipStream_t stream) {
  const float* feat   = (const float*)d_in[0];
  const float* bn1_g  = (const float*)d_in[1];
  const float* bn1_b  = (const float*)d_in[2];
  const float* W_emb  = (const float*)d_in[3];
  const float* embn_g = (const float*)d_in[4];
  const float* embn_b = (const float*)d_in[5];
  const float* W_msg  = (const float*)d_in[6];
  const float* W1 = (const float*)d_in[7];
  const float* b1 = (const float*)d_in[8];
  const float* W2 = (const float*)d_in[9];
  const float* b2 = (const float*)d_in[10];
  const float* W3 = (const float*)d_in[11];
  const float* b3 = (const float*)d_in[12];
  const float* bn2_g = (const float*)d_in[13];
  const float* bn2_b = (const float*)d_in[14];
  const float* Wc    = (const float*)d_in[15];

  const int NNODE[4] = {131072, 65536, 32768, 16384};
  const int NEDGE[4] = {917504, 458752, 229376, 114688};
  const int N = cN0;
  const int SBLK = 256;   // colstats partial blocks
  const int BN1B = 64;    // bn1 partial blocks

  // ---- workspace arena (256B-aligned) ----
  size_t off = 0;
  char* base = (char*)d_ws;
  auto af = [&](size_t nf) -> float* { float* p = (float*)(base + off); off += ((nf*4 + 255) & ~(size_t)255); return p; };
  auto ai = [&](size_t ni) -> int*   { int*   p = (int*)  (base + off); off += ((ni*4 + 255) & ~(size_t)255); return p; };

  int* hist   = ai((size_t)NWG * NBINS);
  int* offs   = ai((size_t)NBINS * NWG);
  int* total  = ai(NBINS);
  int* bbase  = ai(NBINS + 1);
  int* pairs  = ai(NEDGE_TOT);

  float* pacc1 = af((size_t)BN1B * 12);
  float* pacce = af((size_t)SBLK * 160);
  float* pacc2 = af((size_t)SBLK * 128);
  float* ss1 = af(12);
  float* sse = af(160);
  float* wcp = af(64*13 + 13);
  int* rp[4];   for (int l = 0; l < 4; l++) rp[l]   = ai(NNODE[l] + 1);
  int* col[4];  for (int l = 0; l < 4; l++) col[l]  = ai(NEDGE[l]);

  float* t_h0 = af((size_t)N * HID);     // t -> h0 in place; later hud0 ping (H0P)
  float* hWb  = af((size_t)N * HID);     // hW per level; later hud0 pong (H0Q)
  float* f[4];
  f[0] = af((size_t)NNODE[0] * HID);
  f[1] = af((size_t)NNODE[1] * HID);
  f[2] = af((size_t)NNODE[2] * HID);
  f[3] = af((size_t)NNODE[3] * HID);
  float* h1a = af((size_t)NNODE[1] * HID);
  float* h1b = af((size_t)NNODE[1] * HID);
  float* h2a = af((size_t)NNODE[2] * HID);
  float* h2b = af((size_t)NNODE[2] * HID);
  float* h3  = af((size_t)NNODE[3] * HID);

  float* x1 = f[0];           // N*64 fits in f0's N*80
  float* x2 = f[1];           // N*64 fits in f1+f2+f3 span
  float* x3 = f[0];
  (void)ws_size; (void)in_sizes; (void)n_in; (void)out_size;

  // ---- bn1 -> scale/shift; embed; embn -> scale/shift; relu ----
  k_bn1_stats<<<BN1B, 256, 0, stream>>>(feat, pacc1);
  k_finalize<<<1, 64, 0, stream>>>(pacc1, BN1B, bn1_g, bn1_b, ss1, 6, 1.f / N);
  k_emb4<<<(N * (HID/4)) / 256, 256, 0, stream>>>(feat, W_emb, ss1, t_h0);
  k_colstats<<<SBLK, 320, 2*80*4, stream>>>(t_h0, N, 80, pacce);
  k_finalize<<<1, 128, 0, stream>>>(pacce, SBLK, embn_g, embn_b, sse, 80, 1.f / N);
  k_scale_relu4<<<(N * (HID/4)) / 256, 256, 0, stream>>>(t_h0, sse, N * (HID/4));

  // ---- binned CSR build, deterministic: 5 launches, no global atomics ----
  BinP bp;
  for (int l = 0; l < 4; l++) {
    bp.ii[l] = (const int*)d_in[16 + 2*l];
    bp.jj[l] = (const int*)d_in[17 + 2*l];
    bp.rp[l] = rp[l]; bp.col[l] = col[l];
  }
  bp.hist = hist; bp.offs = offs; bp.total = total; bp.base = bbase; bp.pairs = pairs;
  k_binA<<<NWG, 256, 0, stream>>>(bp);
  k_binT<<<NBINS, 256, 0, stream>>>(bp);
  k_binScan2<<<1, 256, 0, stream>>>(bp);
  k_binB<<<NWG, 256, 0, stream>>>(bp);
  k_binCSR<<<NBINS, 256, 0, stream>>>(bp);

  // ---- features per level: hW = h @ W_msg[l]; f = elu(h + csr_sum(hW)) ----
  const float* hin = t_h0;
  for (int l = 0; l < 4; l++) {
    int n = NNODE[l];
    k_gemm<80, 80, false><<<n / 64, 256, 0, stream>>>(hin, W_msg + (size_t)l * HID * HID, nullptr, hWb);
    k_agg_elu4<<<(n * (HID/4)) / 256, 256, 0, stream>>>(hin, hWb, rp[l], col[l], f[l], n);
    hin = f[l];
  }

  // ---- propagation: 10 unrolled segment-sums with conditional-source mix ----
  float* H0P = t_h0;  // h0 dead after features phase
  float* H0Q = hWb;   // hW dead after features phase
  const int B = 256;
  // l=0
  k_prop4<<<(NNODE[0]*(HID/4))/B, B, 0, stream>>>(f[0], f[0], NNODE[0], rp[0], col[0], H0P, NNODE[0]);
  // l=1
  k_prop4<<<(NNODE[1]*(HID/4))/B, B, 0, stream>>>(f[1], f[1], NNODE[1], rp[1], col[1], h1a, NNODE[1]);
  k_prop4<<<(NNODE[0]*(HID/4))/B, B, 0, stream>>>(h1a, H0P, 65536, rp[0], col[0], H0Q, NNODE[0]);
  // l=2
  k_prop4<<<(NNODE[2]*(HID/4))/B, B, 0, stream>>>(f[2], f[2], NNODE[2], rp[2], col[2], h2a, NNODE[2]);
  k_prop4<<<(NNODE[1]*(HID/4))/B, B, 0, stream>>>(h2a, h1a, 32768, rp[1], col[1], h1b, NNODE[1]);
  k_prop4<<<(NNODE[0]*(HID/4))/B, B, 0, stream>>>(h1b, H0Q, 65536, rp[0], col[0], H0P, NNODE[0]);
  // l=3
  k_prop4<<<(NNODE[3]*(HID/4))/B, B, 0, stream>>>(f[3], f[3], NNODE[3], rp[3], col[3], h3, NNODE[3]);
  k_prop4<<<(NNODE[2]*(HID/4))/B, B, 0, stream>>>(h3, h2a, 16384, rp[2], col[2], h2b, NNODE[2]);
  k_prop4<<<(NNODE[1]*(HID/4))/B, B, 0, stream>>>(h2b, h1b, 32768, rp[1], col[1], h1a, NNODE[1]);
  k_prop4<<<(NNODE[0]*(HID/4))/B, B, 0, stream>>>(h1a, H0P, 65536, rp[0], col[0], H0Q, NNODE[0]);
  // final h_up_down == H0Q

  // ---- MLP head + bn2 folded into Wc ----
  k_gemm<80, 64, true><<<N / 64, 256, 0, stream>>>(H0Q, W1, b1, x1);
  k_gemm<64, 64, true><<<N / 64, 256, 0, stream>>>(x1, W2, b2, x2);
  k_gemm<64, 64, true><<<N / 64, 256, 0, stream>>>(x2, W3, b3, x3);
  k_colstats<<<SBLK, 256, 2*64*4, stream>>>(x3, N, 64, pacc2);
  k_fin_bn2<<<1, 64, 0, stream>>>(pacc2, SBLK, bn2_g, bn2_b, Wc, wcp);
  k_final<<<(N * 13) / 256, 256, 0, stream>>>(x3, wcp, (float*)d_out);
}

// Round 8
// 929.252 us; speedup vs baseline: 1.7204x; 1.0985x over previous
//
#include <hip/hip_runtime.h>
#include <math.h>

// ---------------------------------------------------------------------------
// FancyNet: 4-level hierarchical GNN + MLP head on MI355X.
//   * hW = h @ W_msg per-node (gather commutes with matmul) -> 7x less GEMM
//   * up_l == arange(N_l/2) => downsample = first-half rows; ".at[up].set(hud)"
//     = conditional-source read (j<half ? top : old)
//   * propagation unrolled to 10 prop kernels with ping-pong buffers
//   * BN folds to scale/shift; bn2 folded into Wc' + bias13
//   * R1 fix: NO contended global float atomics (stats via block partials).
//   * R3 fix: deterministic two-level counting-sort CSR build.
//   * R4/R5 lesson: full-row-in-registers GEMM spills to scratch. Rule #20.
//   * R7 lesson: col-group-fast dispatch spreads row-slice re-reads over 8
//     XCD-private L2s -> 5x HBM re-fetch. Multi-pass reads must be removed
//     structurally, not by dispatch-order tuning.
//   * R8: one-pass gemm (64 rows x ALL cols, A-tile transposed in LDS, W via
//     wave-uniform s_load). 1021us; gemm off the critical list.
//   * R9: the three single-WG finalize kernels were 69us EACH (1 wave
//     looping npart=256 dependent HBM loads; Occupancy 0.01%). ~207us of
//     the 1021. Now 1024-thread WG: nsub parallel partial-chains per column
//     + LDS-atomic reduce -> ~6-10us each.
// ---------------------------------------------------------------------------

#define HID 80
constexpr int cN0 = 131072;

__device__ __forceinline__ float eluf(float x) { return x > 0.f ? x : expm1f(x); }

// ---------------- bn1 stats (6 cols): 2 rows/thread as 3x float4, block partials ----------------
__global__ void k_bn1_stats(const float* __restrict__ feat, float* __restrict__ pacc) {
  float s[6] = {0,0,0,0,0,0}, q[6] = {0,0,0,0,0,0};
  int idx = blockIdx.x * blockDim.x + threadIdx.x;
  int stride = gridDim.x * blockDim.x;
  for (int r2 = idx; r2 < cN0 / 2; r2 += stride) {
    const float4* p = (const float4*)(feat + (size_t)r2 * 12);
    float4 a = p[0], b = p[1], c = p[2];
    s[0] += a.x + b.z;  q[0] += a.x*a.x + b.z*b.z;
    s[1] += a.y + b.w;  q[1] += a.y*a.y + b.w*b.w;
    s[2] += a.z + c.x;  q[2] += a.z*a.z + c.x*c.x;
    s[3] += a.w + c.y;  q[3] += a.w*a.w + c.y*c.y;
    s[4] += b.x + c.z;  q[4] += b.x*b.x + c.z*c.z;
    s[5] += b.y + c.w;  q[5] += b.y*b.y + c.w*c.w;
  }
#pragma unroll
  for (int k = 0; k < 6; k++) {
    for (int off = 32; off; off >>= 1) {
      s[k] += __shfl_down(s[k], off, 64);
      q[k] += __shfl_down(q[k], off, 64);
    }
  }
  __shared__ float ls[4][12];
  int wid = threadIdx.x >> 6;
  if ((threadIdx.x & 63) == 0) {
#pragma unroll
    for (int k = 0; k < 6; k++) { ls[wid][k] = s[k]; ls[wid][6 + k] = q[k]; }
  }
  __syncthreads();
  if (threadIdx.x < 12) {
    pacc[blockIdx.x * 12 + threadIdx.x] =
        ls[0][threadIdx.x] + ls[1][threadIdx.x] + ls[2][threadIdx.x] + ls[3][threadIdx.x];
  }
}

// ---------------- finalize scale/shift from npart block partials (parallel) ----------------
// 1024 threads: thread (c2 = t%2C, sub = t/2C) sums partials p = sub, sub+nsub...
// -> nsub parallel load chains per column instead of 1 (R9: was 69us single-wave).
__global__ void k_finalize(const float* __restrict__ pacc, int npart,
                           const float* __restrict__ g, const float* __restrict__ b,
                           float* __restrict__ ss, int ncols, float inv_n) {
  extern __shared__ float red[];   // 2*ncols
  int C2 = 2 * ncols;
  int t = threadIdx.x;
  int c2 = t % C2;
  int sub = t / C2;
  int nsub = blockDim.x / C2;
  float s = 0.f;
  if (sub < nsub)
    for (int p = sub; p < npart; p += nsub) s += pacc[p * C2 + c2];
  if (t < C2) red[t] = 0.f;
  __syncthreads();
  if (sub < nsub) atomicAdd(&red[c2], s);
  __syncthreads();
  if (t < ncols) {
    float m = red[t] * inv_n;
    float v = red[ncols + t] * inv_n - m * m;
    float sc = g[t] * rsqrtf(v + 1e-5f);
    ss[t] = sc;
    ss[ncols + t] = b[t] - m * sc;
  }
}

// ---------------- embedding: t = bn1(feat) @ W_emb  (6 -> 80) ----------------
__global__ void k_emb4(const float* __restrict__ feat, const float* __restrict__ Wemb,
                       const float* __restrict__ ss, float* __restrict__ t) {
  __shared__ float Wl[6 * HID];
  __shared__ float sc[12];
  for (int i = threadIdx.x; i < 6 * HID; i += blockDim.x) Wl[i] = Wemb[i];
  if (threadIdx.x < 12) sc[threadIdx.x] = ss[threadIdx.x];
  __syncthreads();
  int gid = blockIdx.x * blockDim.x + threadIdx.x;
  if (gid >= cN0 * (HID/4)) return;
  int r = gid / (HID/4);
  int c4 = (gid - r * (HID/4)) * 4;
  float a[6];
#pragma unroll
  for (int k = 0; k < 6; k++) a[k] = feat[r*6 + k] * sc[k] + sc[6 + k];
  float4 o;
  float* op = (float*)&o;
#pragma unroll
  for (int i = 0; i < 4; i++) {
    float v = 0.f;
#pragma unroll
    for (int k = 0; k < 6; k++) v += a[k] * Wl[k*HID + c4 + i];
    op[i] = v;
  }
  *(float4*)(t + (size_t)r*HID + c4) = o;
}

// ---------------- column stats -> per-block partials (LDS atomics only) ----------------
__global__ void k_colstats(const float* __restrict__ x, int nrows, int ncols,
                           float* __restrict__ pacc) {
  extern __shared__ float ls[]; // 2*ncols
  int c = threadIdx.x % ncols;
  int sub = threadIdx.x / ncols;
  int rows_per = blockDim.x / ncols;
  for (int i = threadIdx.x; i < 2*ncols; i += blockDim.x) ls[i] = 0.f;
  __syncthreads();
  float s = 0.f, q = 0.f;
  for (int r = blockIdx.x * rows_per + sub; r < nrows; r += gridDim.x * rows_per) {
    float v = x[(size_t)r * ncols + c];
    s += v; q += v*v;
  }
  atomicAdd(&ls[c], s);
  atomicAdd(&ls[ncols + c], q);
  __syncthreads();
  for (int i = threadIdx.x; i < 2*ncols; i += blockDim.x)
    pacc[blockIdx.x * 2 * ncols + i] = ls[i];
}

// ---------------- in-place scale+shift+relu over 80-col matrix ----------------
__global__ void k_scale_relu4(float* __restrict__ x, const float* __restrict__ ss, int ntot4) {
  int gid = blockIdx.x * blockDim.x + threadIdx.x;
  if (gid >= ntot4) return;
  int r = gid / (HID/4);
  int c4 = (gid - r * (HID/4)) * 4;
  float4 t = *(float4*)(x + (size_t)r*HID + c4);
  float* tp = (float*)&t;
#pragma unroll
  for (int i = 0; i < 4; i++) {
    float v = tp[i] * ss[c4 + i] + ss[HID + c4 + i];
    tp[i] = v > 0.f ? v : 0.f;
  }
  *(float4*)(x + (size_t)r*HID + c4) = t;
}

// ---------------- binned CSR build (deterministic, atomic-free scatter) ----------------
// Bins: 1024 dst nodes each. Level bin counts {128,64,32,16} -> 240 bins total.
#define NBINS 240
#define NEDGE_TOT 1720320
#define BIN_CHUNK 2048   // edges per WG; 1720320/2048 = 840 WGs, level-exact splits
#define NWG 840

struct BinP {
  const int* ii[4]; const int* jj[4];
  int* hist;    // [NWG][NBINS] per-WG bin histograms
  int* offs;    // [NBINS][NWG] exclusive WG-prefix within bin
  int* total;   // [NBINS]
  int* base;    // [NBINS+1] exclusive scan of totals
  int* pairs;   // [NEDGE_TOT] packed (i_local<<17 | j), bin-grouped
  int* rp[4]; int* col[4];
};

__device__ __forceinline__ int edge_level(int gid, int& el) {
  if (gid < 917504)  { el = gid;           return 0; }
  if (gid < 1376256) { el = gid - 917504;  return 1; }
  if (gid < 1605632) { el = gid - 1376256; return 2; }
  el = gid - 1605632; return 3;
}
__device__ __forceinline__ int blk_level(int b, int& lb) {
  if (b < 128) { lb = b;       return 0; }
  if (b < 192) { lb = b - 128; return 1; }
  if (b < 224) { lb = b - 192; return 2; }
  lb = b - 224; return 3;
}
__constant__ const int cNN[4] = {131072, 65536, 32768, 16384};
__constant__ const int cNE[4] = {917504, 458752, 229376, 114688};
__constant__ const int cNB[4] = {128, 64, 32, 16};
__constant__ const int cLB[4] = {0, 128, 192, 224};   // first bin of each level

// Pass A: per-WG LDS histogram over 240 bins -> hist[wg][b] (coalesced write).
__global__ void k_binA(BinP p) {
  __shared__ int h[NBINS];
  for (int i = threadIdx.x; i < NBINS; i += 256) h[i] = 0;
  __syncthreads();
  int ebase = blockIdx.x * BIN_CHUNK;
#pragma unroll
  for (int it = 0; it < BIN_CHUNK / 256; it++) {
    int e = ebase + it * 256 + threadIdx.x;
    int el; int l = edge_level(e, el);
    atomicAdd(&h[cLB[l] + (p.ii[l][el] >> 10)], 1);
  }
  __syncthreads();
  for (int b = threadIdx.x; b < NBINS; b += 256)
    p.hist[blockIdx.x * NBINS + b] = h[b];
}

// Pass T: one WG per bin. Exclusive scan of hist[:,b] over the 840 WGs.
__global__ void k_binT(BinP p) {
  __shared__ int sd[256];
  int b = blockIdx.x;
  int t = threadIdx.x;
  int carry = 0;
  for (int r = 0; r < 4; r++) {
    int idx = r * 256 + t;
    int v = (idx < NWG) ? p.hist[idx * NBINS + b] : 0;
    sd[t] = v;
    __syncthreads();
    for (int off = 1; off < 256; off <<= 1) {
      int x = sd[t];
      if (t >= off) x += sd[t - off];
      __syncthreads();
      sd[t] = x;
      __syncthreads();
    }
    if (idx < NWG) p.offs[b * NWG + idx] = carry + sd[t] - v;  // exclusive
    carry += sd[255];
    __syncthreads();
  }
  if (t == 0) p.total[b] = carry;
}

// Pass S: 1 WG, exclusive scan of 240 bin totals -> base[241].
__global__ void k_binScan2(BinP p) {
  __shared__ int sd[256];
  int t = threadIdx.x;
  int v = (t < NBINS) ? p.total[t] : 0;
  sd[t] = v;
  __syncthreads();
  for (int off = 1; off < 256; off <<= 1) {
    int x = sd[t];
    if (t >= off) x += sd[t - off];
    __syncthreads();
    sd[t] = x;
    __syncthreads();
  }
  if (t < NBINS) p.base[t] = sd[t] - v;
  if (t == NBINS - 1) p.base[NBINS] = sd[t];
}

// Pass B: deterministic scatter. LDS cursors seeded with base[b]+offs[b][wg];
// per-edge LDS atomicAdd + plain global store. Each (bin,wg) mini-segment
// (~1 line) is written by exactly one WG -> lines merge in L2.
__global__ void k_binB(BinP p) {
  __shared__ int cur[NBINS];
  int wg = blockIdx.x;
  for (int b = threadIdx.x; b < NBINS; b += 256)
    cur[b] = p.base[b] + p.offs[b * NWG + wg];
  __syncthreads();
  int ebase = wg * BIN_CHUNK;
#pragma unroll
  for (int it = 0; it < BIN_CHUNK / 256; it++) {
    int e = ebase + it * 256 + threadIdx.x;
    int el; int l = edge_level(e, el);
    int i = p.ii[l][el], j = p.jj[l][el];
    int b = cLB[l] + (i >> 10);
    int gpos = atomicAdd(&cur[b], 1);
    p.pairs[gpos] = ((i & 1023) << 17) | j;   // j < 131072 -> 17 bits
  }
}

// Pass D: one WG per bin. LDS degree count + scan -> rp (coalesced int4),
// LDS cursors -> col scatter confined to this bin's contiguous ~28KB region.
__global__ void __launch_bounds__(256) k_binCSR(BinP p) {
  __shared__ int d[1024];
  __shared__ int sd[256];
  int lb; int l = blk_level(blockIdx.x, lb);
  int t = threadIdx.x;
  int e0g = p.base[blockIdx.x];
  int e1g = p.base[blockIdx.x + 1];
  int lvlbase = p.base[cLB[l]];
  int e0 = e0g - lvlbase;               // level-local edge base of this bin
  for (int i = t; i < 1024; i += 256) d[i] = 0;
  __syncthreads();
  for (int e = e0g + t; e < e1g; e += 256)
    atomicAdd(&d[p.pairs[e] >> 17], 1);
  __syncthreads();
  int a0 = d[4*t], a1 = d[4*t+1], a2 = d[4*t+2], a3 = d[4*t+3];
  int ts = a0 + a1 + a2 + a3;
  sd[t] = ts;
  __syncthreads();
  for (int off = 1; off < 256; off <<= 1) {
    int x = sd[t];
    if (t >= off) x += sd[t - off];
    __syncthreads();
    sd[t] = x;
    __syncthreads();
  }
  int c0 = e0 + sd[t] - ts;             // level-local exclusive prefix
  int c1 = c0 + a0, c2 = c1 + a1, c3 = c2 + a2;
  int* rp = p.rp[l];
  *(int4*)(rp + lb * 1024 + 4 * t) = make_int4(c0, c1, c2, c3);
  if (t == 0 && lb == cNB[l] - 1) rp[cNN[l]] = cNE[l];
  d[4*t] = c0; d[4*t+1] = c1; d[4*t+2] = c2; d[4*t+3] = c3;   // cursors
  __syncthreads();
  int* col = p.col[l];
  for (int e = e0g + t; e < e1g; e += 256) {
    int pk = p.pairs[e];
    int slot = atomicAdd(&d[pk >> 17], 1);
    col[slot] = pk & 0x1FFFF;
  }
}

// ---------------- GEMM: out = act(in @ W + bias), one-pass, A-tile in LDS ----------------
// Block = 64 rows x ALL KOUT cols; input read exactly once. A staged
// TRANSPOSED (As[k][64]): staging coalesced, per-k wave read = 64 consecutive
// floats (conflict-free). W read via wave-uniform scalar loads: c0 forced to
// SGPR with readfirstlane -> s_load. Vector pipe per k: 1 ds_read + CPT FMAs.
template <int KIN, int KOUT, bool ELU>
__global__ void __launch_bounds__(256) k_gemm(const float* __restrict__ in,
                                              const float* __restrict__ W,
                                              const float* __restrict__ bias,
                                              float* __restrict__ out) {
  constexpr int CPT = KOUT / 4;          // cols per thread (4 waves cover KOUT)
  __shared__ float As[KIN * 64];
  int rbase = blockIdx.x * 64;
  // stage 64 rows x KIN, transposed into As[k][row]
  for (int idx = threadIdx.x; idx < 16 * KIN; idx += 256) {
    int r = idx / (KIN / 4);
    int q = idx - r * (KIN / 4);
    float4 v = *(const float4*)(in + (size_t)(rbase + r) * KIN + q * 4);
    As[(q * 4 + 0) * 64 + r] = v.x;
    As[(q * 4 + 1) * 64 + r] = v.y;
    As[(q * 4 + 2) * 64 + r] = v.z;
    As[(q * 4 + 3) * 64 + r] = v.w;
  }
  __syncthreads();
  int row = threadIdx.x & 63;
  int c0 = __builtin_amdgcn_readfirstlane((threadIdx.x >> 6) * CPT);
  float acc[CPT];
#pragma unroll
  for (int i = 0; i < CPT; i++) acc[i] = bias ? bias[c0 + i] : 0.f;
#pragma unroll 4
  for (int k = 0; k < KIN; k++) {
    float a = As[k * 64 + row];
    const float* wk = W + (size_t)k * KOUT + c0;   // uniform -> s_load
#pragma unroll
    for (int i = 0; i < CPT; i++) acc[i] += a * wk[i];
  }
  float* orow = out + (size_t)(rbase + row) * KOUT + c0;
#pragma unroll
  for (int u = 0; u < CPT / 4; u++) {
    float v0 = acc[4*u+0], v1 = acc[4*u+1], v2 = acc[4*u+2], v3 = acc[4*u+3];
    if (ELU) {
      v0 = v0 > 0.f ? v0 : expm1f(v0);  v1 = v1 > 0.f ? v1 : expm1f(v1);
      v2 = v2 > 0.f ? v2 : expm1f(v2);  v3 = v3 > 0.f ? v3 : expm1f(v3);
    }
    float4 o; o.x = v0; o.y = v1; o.z = v2; o.w = v3;
    *(float4*)(orow + 4 * u) = o;
  }
}

// ---------------- f = elu(h + CSR-gather-sum(hW)), float4 per thread ----------------
__global__ void k_agg_elu4(const float* __restrict__ h, const float* __restrict__ hW,
                           const int* __restrict__ rp, const int* __restrict__ col,
                           float* __restrict__ f, int n) {
  int gid = blockIdx.x * blockDim.x + threadIdx.x;
  if (gid >= n * (HID/4)) return;
  int v = gid / (HID/4);
  int c4 = (gid - v * (HID/4)) * 4;
  int e0 = rp[v], e1 = rp[v + 1];
  float4 s = *(const float4*)(h + (size_t)v*HID + c4);
  float* sp = (float*)&s;
  for (int e = e0; e < e1; e++) {
    int j = col[e];
    float4 x = *(const float4*)(hW + (size_t)j*HID + c4);
    sp[0] += x.x; sp[1] += x.y; sp[2] += x.z; sp[3] += x.w;
  }
#pragma unroll
  for (int i = 0; i < 4; i++) sp[i] = eluf(sp[i]);
  *(float4*)(f + (size_t)v*HID + c4) = s;
}

// ---------------- dst[v] = sum over CSR of src[j], src = (j<half ? top : old) ----------------
__global__ void k_prop4(const float* __restrict__ top, const float* __restrict__ oldb,
                        int half, const int* __restrict__ rp, const int* __restrict__ col,
                        float* __restrict__ dst, int n) {
  int gid = blockIdx.x * blockDim.x + threadIdx.x;
  if (gid >= n * (HID/4)) return;
  int v = gid / (HID/4);
  int c4 = (gid - v * (HID/4)) * 4;
  int e0 = rp[v], e1 = rp[v + 1];
  float4 s = {0,0,0,0};
  float* sp = (float*)&s;
  for (int e = e0; e < e1; e++) {
    int j = col[e];
    const float* src = (j < half) ? top : oldb;
    float4 x = *(const float4*)(src + (size_t)j*HID + c4);
    sp[0] += x.x; sp[1] += x.y; sp[2] += x.z; sp[3] += x.w;
  }
  *(float4*)(dst + (size_t)v*HID + c4) = s;
}

// ---------------- finalize bn2 (parallel) and fold into Wc ----------------
// 1024 threads: 8 parallel chains per column over the 256 partials (R9).
__global__ void k_fin_bn2(const float* __restrict__ pacc, int npart,
                          const float* __restrict__ g, const float* __restrict__ b,
                          const float* __restrict__ Wc, float* __restrict__ wcp) {
  __shared__ float red[128];
  __shared__ float sc[64], sh[64];
  int t = threadIdx.x;           // 1024
  int c2 = t & 127;
  int sub = t >> 7;              // 0..7
  float s = 0.f;
  for (int p = sub; p < npart; p += 8) s += pacc[p * 128 + c2];
  if (t < 128) red[t] = 0.f;
  __syncthreads();
  atomicAdd(&red[c2], s);
  __syncthreads();
  if (t < 64) {
    float invn = 1.f / (float)cN0;
    float m = red[t] * invn;
    float v = red[64 + t] * invn - m * m;
    float scv = g[t] * rsqrtf(v + 1e-5f);
    sc[t] = scv;
    sh[t] = b[t] - m * scv;
  }
  __syncthreads();
  for (int i = t; i < 64 * 13; i += 1024) { int c = i / 13; wcp[i] = sc[c] * Wc[i]; }
  if (t < 13) {
    float acc13 = 0.f;
    for (int c = 0; c < 64; c++) acc13 += sh[c] * Wc[c*13 + t];
    wcp[64*13 + t] = acc13;
  }
}

// ---------------- final: out = bn2(x3) @ Wc  == x3 @ Wc' + bias13 ----------------
__global__ void k_final(const float* __restrict__ x3, const float* __restrict__ wcp,
                        float* __restrict__ out) {
  __shared__ float Wl[64*13 + 13];
  for (int i = threadIdx.x; i < 64*13 + 13; i += blockDim.x) Wl[i] = wcp[i];
  __syncthreads();
  int gid = blockIdx.x * blockDim.x + threadIdx.x; // exactly N0*13
  int r = gid / 13, o = gid - r * 13;
  const float* row = x3 + (size_t)r * 64;
  float s = Wl[64*13 + o];
#pragma unroll
  for (int c = 0; c < 64; c++) s += row[c] * Wl[c*13 + o];
  out[gid] = s;
}

// ===========================================================================
extern "C" void kernel_launch(void* const* d_in, const int* in_sizes, int n_in,
                              void* d_out, int out_size, void* d_ws, size_t ws_size,
                              hipStream_t stream) {
  const float* feat   = (const float*)d_in[0];
  const float* bn1_g  = (const float*)d_in[1];
  const float* bn1_b  = (const float*)d_in[2];
  const float* W_emb  = (const float*)d_in[3];
  const float* embn_g = (const float*)d_in[4];
  const float* embn_b = (const float*)d_in[5];
  const float* W_msg  = (const float*)d_in[6];
  const float* W1 = (const float*)d_in[7];
  const float* b1 = (const float*)d_in[8];
  const float* W2 = (const float*)d_in[9];
  const float* b2 = (const float*)d_in[10];
  const float* W3 = (const float*)d_in[11];
  const float* b3 = (const float*)d_in[12];
  const float* bn2_g = (const float*)d_in[13];
  const float* bn2_b = (const float*)d_in[14];
  const float* Wc    = (const float*)d_in[15];

  const int NNODE[4] = {131072, 65536, 32768, 16384};
  const int NEDGE[4] = {917504, 458752, 229376, 114688};
  const int N = cN0;
  const int SBLK = 256;   // colstats partial blocks
  const int BN1B = 64;    // bn1 partial blocks

  // ---- workspace arena (256B-aligned) ----
  size_t off = 0;
  char* base = (char*)d_ws;
  auto af = [&](size_t nf) -> float* { float* p = (float*)(base + off); off += ((nf*4 + 255) & ~(size_t)255); return p; };
  auto ai = [&](size_t ni) -> int*   { int*   p = (int*)  (base + off); off += ((ni*4 + 255) & ~(size_t)255); return p; };

  int* hist   = ai((size_t)NWG * NBINS);
  int* offs   = ai((size_t)NBINS * NWG);
  int* total  = ai(NBINS);
  int* bbase  = ai(NBINS + 1);
  int* pairs  = ai(NEDGE_TOT);

  float* pacc1 = af((size_t)BN1B * 12);
  float* pacce = af((size_t)SBLK * 160);
  float* pacc2 = af((size_t)SBLK * 128);
  float* ss1 = af(12);
  float* sse = af(160);
  float* wcp = af(64*13 + 13);
  int* rp[4];   for (int l = 0; l < 4; l++) rp[l]   = ai(NNODE[l] + 1);
  int* col[4];  for (int l = 0; l < 4; l++) col[l]  = ai(NEDGE[l]);

  float* t_h0 = af((size_t)N * HID);     // t -> h0 in place; later hud0 ping (H0P)
  float* hWb  = af((size_t)N * HID);     // hW per level; later hud0 pong (H0Q)
  float* f[4];
  f[0] = af((size_t)NNODE[0] * HID);
  f[1] = af((size_t)NNODE[1] * HID);
  f[2] = af((size_t)NNODE[2] * HID);
  f[3] = af((size_t)NNODE[3] * HID);
  float* h1a = af((size_t)NNODE[1] * HID);
  float* h1b = af((size_t)NNODE[1] * HID);
  float* h2a = af((size_t)NNODE[2] * HID);
  float* h2b = af((size_t)NNODE[2] * HID);
  float* h3  = af((size_t)NNODE[3] * HID);

  float* x1 = f[0];           // N*64 fits in f0's N*80
  float* x2 = f[1];           // N*64 fits in f1+f2+f3 span
  float* x3 = f[0];
  (void)ws_size; (void)in_sizes; (void)n_in; (void)out_size;

  // ---- bn1 -> scale/shift; embed; embn -> scale/shift; relu ----
  k_bn1_stats<<<BN1B, 256, 0, stream>>>(feat, pacc1);
  k_finalize<<<1, 1024, 2*6*4, stream>>>(pacc1, BN1B, bn1_g, bn1_b, ss1, 6, 1.f / N);
  k_emb4<<<(N * (HID/4)) / 256, 256, 0, stream>>>(feat, W_emb, ss1, t_h0);
  k_colstats<<<SBLK, 320, 2*80*4, stream>>>(t_h0, N, 80, pacce);
  k_finalize<<<1, 1024, 2*80*4, stream>>>(pacce, SBLK, embn_g, embn_b, sse, 80, 1.f / N);
  k_scale_relu4<<<(N * (HID/4)) / 256, 256, 0, stream>>>(t_h0, sse, N * (HID/4));

  // ---- binned CSR build, deterministic: 5 launches, no global atomics ----
  BinP bp;
  for (int l = 0; l < 4; l++) {
    bp.ii[l] = (const int*)d_in[16 + 2*l];
    bp.jj[l] = (const int*)d_in[17 + 2*l];
    bp.rp[l] = rp[l]; bp.col[l] = col[l];
  }
  bp.hist = hist; bp.offs = offs; bp.total = total; bp.base = bbase; bp.pairs = pairs;
  k_binA<<<NWG, 256, 0, stream>>>(bp);
  k_binT<<<NBINS, 256, 0, stream>>>(bp);
  k_binScan2<<<1, 256, 0, stream>>>(bp);
  k_binB<<<NWG, 256, 0, stream>>>(bp);
  k_binCSR<<<NBINS, 256, 0, stream>>>(bp);

  // ---- features per level: hW = h @ W_msg[l]; f = elu(h + csr_sum(hW)) ----
  const float* hin = t_h0;
  for (int l = 0; l < 4; l++) {
    int n = NNODE[l];
    k_gemm<80, 80, false><<<n / 64, 256, 0, stream>>>(hin, W_msg + (size_t)l * HID * HID, nullptr, hWb);
    k_agg_elu4<<<(n * (HID/4)) / 256, 256, 0, stream>>>(hin, hWb, rp[l], col[l], f[l], n);
    hin = f[l];
  }

  // ---- propagation: 10 unrolled segment-sums with conditional-source mix ----
  float* H0P = t_h0;  // h0 dead after features phase
  float* H0Q = hWb;   // hW dead after features phase
  const int B = 256;
  // l=0
  k_prop4<<<(NNODE[0]*(HID/4))/B, B, 0, stream>>>(f[0], f[0], NNODE[0], rp[0], col[0], H0P, NNODE[0]);
  // l=1
  k_prop4<<<(NNODE[1]*(HID/4))/B, B, 0, stream>>>(f[1], f[1], NNODE[1], rp[1], col[1], h1a, NNODE[1]);
  k_prop4<<<(NNODE[0]*(HID/4))/B, B, 0, stream>>>(h1a, H0P, 65536, rp[0], col[0], H0Q, NNODE[0]);
  // l=2
  k_prop4<<<(NNODE[2]*(HID/4))/B, B, 0, stream>>>(f[2], f[2], NNODE[2], rp[2], col[2], h2a, NNODE[2]);
  k_prop4<<<(NNODE[1]*(HID/4))/B, B, 0, stream>>>(h2a, h1a, 32768, rp[1], col[1], h1b, NNODE[1]);
  k_prop4<<<(NNODE[0]*(HID/4))/B, B, 0, stream>>>(h1b, H0Q, 65536, rp[0], col[0], H0P, NNODE[0]);
  // l=3
  k_prop4<<<(NNODE[3]*(HID/4))/B, B, 0, stream>>>(f[3], f[3], NNODE[3], rp[3], col[3], h3, NNODE[3]);
  k_prop4<<<(NNODE[2]*(HID/4))/B, B, 0, stream>>>(h3, h2a, 16384, rp[2], col[2], h2b, NNODE[2]);
  k_prop4<<<(NNODE[1]*(HID/4))/B, B, 0, stream>>>(h2b, h1b, 32768, rp[1], col[1], h1a, NNODE[1]);
  k_prop4<<<(NNODE[0]*(HID/4))/B, B, 0, stream>>>(h1a, H0P, 65536, rp[0], col[0], H0Q, NNODE[0]);
  // final h_up_down == H0Q

  // ---- MLP head + bn2 folded into Wc ----
  k_gemm<80, 64, true><<<N / 64, 256, 0, stream>>>(H0Q, W1, b1, x1);
  k_gemm<64, 64, true><<<N / 64, 256, 0, stream>>>(x1, W2, b2, x2);
  k_gemm<64, 64, true><<<N / 64, 256, 0, stream>>>(x2, W3, b3, x3);
  k_colstats<<<SBLK, 256, 2*64*4, stream>>>(x3, N, 64, pacc2);
  k_fin_bn2<<<1, 1024, 0, stream>>>(pacc2, SBLK, bn2_g, bn2_b, Wc, wcp);
  k_final<<<(N * 13) / 256, 256, 0, stream>>>(x3, wcp, (float*)d_out);
}

// Round 10
// 805.937 us; speedup vs baseline: 1.9837x; 1.1530x over previous
//
#include <hip/hip_runtime.h>
#include <math.h>

// ---------------------------------------------------------------------------
// FancyNet: 4-level hierarchical GNN + MLP head on MI355X.
//   * hW = h @ W_msg per-node (gather commutes with matmul) -> 7x less GEMM
//   * up_l == arange(N_l/2) => downsample = first-half rows
//   * BN folds to scale/shift; bn2 folded into Wc' + bias13
//   * R1: no contended global float atomics. R3: deterministic counting-sort
//     CSR build. R4/R5: no big register arrays (scratch spill, rule #20).
//   * R7 lesson: multi-pass input reads can't be fixed by dispatch order
//     (8 XCD-private L2s); R8: one-pass gemm (A-tile transposed in LDS,
//     W via wave-uniform s_load). R9: parallel finalize (was 69us/WG-serial).
//   * R10a: bn1+embn ANALYTIC FOLD. bn1 output has exactly-zero empirical
//     column means; var of t = bn1(feat)@W_emb is the quadratic form
//     w^T C w over the 6x6 covariance of normalized feat. k_bn1_stats
//     accumulates 27 moments; k_fold emits fused 6x80 weight + bias so
//     h = relu(feat @ W^ + b^). DELETES colstats(80), scale_relu, finalize.
//   * R10b: 10 prop launches -> 4 grouped k_prop_multi launches (job DAG:
//     {P1,P2,P4,P7},{P3,P5,P8},{P6,P9},{P10}); body identical to k_prop4.
//   * R11 lesson: HOST code must not read __constant__ arrays (clang/HIP
//     hard error -> missing symbol -> harness abort). Keep host-local copies
//     of any table the launcher needs (NEDGE below).
//   * NOTE: 21-31ms top-dispatch entries for gather kernels in rocprof are
//     replay artifacts (whole run <1ms); trust FETCH/WRITE + wall dur.
// ---------------------------------------------------------------------------

#define HID 80
constexpr int cN0 = 131072;

__device__ __forceinline__ float eluf(float x) { return x > 0.f ? x : expm1f(x); }

// ---------------- bn1 stats: 27 moments (6 sum, 6 sq, 15 cross), block partials ----------------
__global__ void k_bn1_stats(const float* __restrict__ feat, float* __restrict__ pacc) {
  float s[6] = {0,0,0,0,0,0}, q[6] = {0,0,0,0,0,0};
  float cp[15] = {0,0,0,0,0,0,0,0,0,0,0,0,0,0,0};
  int idx = blockIdx.x * blockDim.x + threadIdx.x;
  int stride = gridDim.x * blockDim.x;
  for (int r2 = idx; r2 < cN0 / 2; r2 += stride) {
    const float4* p = (const float4*)(feat + (size_t)r2 * 12);
    float4 a = p[0], b = p[1], c = p[2];
    float f0[6], f1[6];
    f0[0]=a.x; f0[1]=a.y; f0[2]=a.z; f0[3]=a.w; f0[4]=b.x; f0[5]=b.y;
    f1[0]=b.z; f1[1]=b.w; f1[2]=c.x; f1[3]=c.y; f1[4]=c.z; f1[5]=c.w;
#pragma unroll
    for (int k = 0; k < 6; k++) {
      s[k] += f0[k] + f1[k];
      q[k] += f0[k]*f0[k] + f1[k]*f1[k];
    }
    int ci = 0;
#pragma unroll
    for (int k = 0; k < 6; k++)
#pragma unroll
      for (int k2 = k + 1; k2 < 6; k2++) {
        cp[ci] += f0[k]*f0[k2] + f1[k]*f1[k2];
        ci++;
      }
  }
#pragma unroll
  for (int k = 0; k < 6; k++) {
    for (int off = 32; off; off >>= 1) {
      s[k] += __shfl_down(s[k], off, 64);
      q[k] += __shfl_down(q[k], off, 64);
    }
  }
#pragma unroll
  for (int k = 0; k < 15; k++) {
    for (int off = 32; off; off >>= 1) cp[k] += __shfl_down(cp[k], off, 64);
  }
  __shared__ float ls[4][27];
  int wid = threadIdx.x >> 6;
  if ((threadIdx.x & 63) == 0) {
#pragma unroll
    for (int k = 0; k < 6; k++) { ls[wid][k] = s[k]; ls[wid][6 + k] = q[k]; }
#pragma unroll
    for (int k = 0; k < 15; k++) ls[wid][12 + k] = cp[k];
  }
  __syncthreads();
  if (threadIdx.x < 27) {
    pacc[blockIdx.x * 27 + threadIdx.x] =
        ls[0][threadIdx.x] + ls[1][threadIdx.x] + ls[2][threadIdx.x] + ls[3][threadIdx.x];
  }
}

// ---------------- fold bn1+emb+embn into fused 6x80 weight + bias ----------------
// t = bn1(feat)@W has zero-mean columns up to the b1-term (cancels under
// embn's mean-subtraction); var_c = w^T C w with C = cov of normalized feat.
// Emits fw[k*80+c], fw[480+c] s.t. h = relu(feat @ fw + bias). Exact.
__global__ void k_fold(const float* __restrict__ pacc, int npart,
                       const float* __restrict__ g1, const float* __restrict__ eg,
                       const float* __restrict__ eb, const float* __restrict__ Wemb,
                       float* __restrict__ fw) {
  __shared__ float mom[27];
  __shared__ float m6[6], grs[6];
  __shared__ float Ch[6][6];
  int t = threadIdx.x;
  if (t < 27) {
    float s = 0.f;
    for (int p = 0; p < npart; p++) s += pacc[p * 27 + t];
    mom[t] = s;
  }
  __syncthreads();
  const float invn = 1.f / (float)cN0;
  if (t < 6) {
    float m = mom[t] * invn;
    float v = mom[6 + t] * invn - m * m;
    m6[t] = m;
    grs[t] = g1[t] * rsqrtf(v + 1e-5f);   // g_k * rs_k
  }
  __syncthreads();
  if (t < 36) {
    int k = t / 6, k2 = t % 6;
    float S;
    if (k == k2) S = mom[6 + k];
    else {
      int a = k < k2 ? k : k2, b = k < k2 ? k2 : k;
      int idx = 12 + 5 * a - (a * (a - 1)) / 2 + (b - a - 1);
      S = mom[idx];
    }
    Ch[k][k2] = (S * invn - m6[k] * m6[k2]) * grs[k] * grs[k2];
  }
  __syncthreads();
  for (int c = t; c < HID; c += blockDim.x) {
    float w[6];
#pragma unroll
    for (int k = 0; k < 6; k++) w[k] = Wemb[k * HID + c];
    float var = 0.f;
#pragma unroll
    for (int k = 0; k < 6; k++)
#pragma unroll
      for (int k2 = 0; k2 < 6; k2++) var += w[k] * w[k2] * Ch[k][k2];
    float A = eg[c] * rsqrtf(var + 1e-5f);
    float dot = 0.f;
#pragma unroll
    for (int k = 0; k < 6; k++) dot += grs[k] * m6[k] * w[k];
#pragma unroll
    for (int k = 0; k < 6; k++) fw[k * HID + c] = grs[k] * A * w[k];
    fw[6 * HID + c] = eb[c] - A * dot;
  }
}

// ---------------- embedding: h = relu(feat @ fw + bias)  (6 -> 80, fused) ----------------
__global__ void k_emb4(const float* __restrict__ feat, const float* __restrict__ fw,
                       float* __restrict__ h) {
  __shared__ float Wl[6 * HID];
  __shared__ float bl[HID];
  for (int i = threadIdx.x; i < 6 * HID; i += blockDim.x) Wl[i] = fw[i];
  if (threadIdx.x < HID) bl[threadIdx.x] = fw[6 * HID + threadIdx.x];
  __syncthreads();
  int gid = blockIdx.x * blockDim.x + threadIdx.x;
  if (gid >= cN0 * (HID/4)) return;
  int r = gid / (HID/4);
  int c4 = (gid - r * (HID/4)) * 4;
  float a[6];
#pragma unroll
  for (int k = 0; k < 6; k++) a[k] = feat[r*6 + k];
  float4 o;
  float* op = (float*)&o;
#pragma unroll
  for (int i = 0; i < 4; i++) {
    float v = bl[c4 + i];
#pragma unroll
    for (int k = 0; k < 6; k++) v += a[k] * Wl[k*HID + c4 + i];
    op[i] = v > 0.f ? v : 0.f;
  }
  *(float4*)(h + (size_t)r*HID + c4) = o;
}

// ---------------- column stats -> per-block partials (LDS atomics only) ----------------
__global__ void k_colstats(const float* __restrict__ x, int nrows, int ncols,
                           float* __restrict__ pacc) {
  extern __shared__ float ls[]; // 2*ncols
  int c = threadIdx.x % ncols;
  int sub = threadIdx.x / ncols;
  int rows_per = blockDim.x / ncols;
  for (int i = threadIdx.x; i < 2*ncols; i += blockDim.x) ls[i] = 0.f;
  __syncthreads();
  float s = 0.f, q = 0.f;
  for (int r = blockIdx.x * rows_per + sub; r < nrows; r += gridDim.x * rows_per) {
    float v = x[(size_t)r * ncols + c];
    s += v; q += v*v;
  }
  atomicAdd(&ls[c], s);
  atomicAdd(&ls[ncols + c], q);
  __syncthreads();
  for (int i = threadIdx.x; i < 2*ncols; i += blockDim.x)
    pacc[blockIdx.x * 2 * ncols + i] = ls[i];
}

// ---------------- binned CSR build (deterministic, atomic-free scatter) ----------------
#define NBINS 240
#define NEDGE_TOT 1720320
#define BIN_CHUNK 2048
#define NWG 840

struct BinP {
  const int* ii[4]; const int* jj[4];
  int* hist; int* offs; int* total; int* base; int* pairs;
  int* rp[4]; int* col[4];
};

__device__ __forceinline__ int edge_level(int gid, int& el) {
  if (gid < 917504)  { el = gid;           return 0; }
  if (gid < 1376256) { el = gid - 917504;  return 1; }
  if (gid < 1605632) { el = gid - 1376256; return 2; }
  el = gid - 1605632; return 3;
}
__device__ __forceinline__ int blk_level(int b, int& lb) {
  if (b < 128) { lb = b;       return 0; }
  if (b < 192) { lb = b - 128; return 1; }
  if (b < 224) { lb = b - 192; return 2; }
  lb = b - 224; return 3;
}
__constant__ const int cNN[4] = {131072, 65536, 32768, 16384};
__constant__ const int cNE[4] = {917504, 458752, 229376, 114688};
__constant__ const int cNB[4] = {128, 64, 32, 16};
__constant__ const int cLB[4] = {0, 128, 192, 224};

__global__ void k_binA(BinP p) {
  __shared__ int h[NBINS];
  for (int i = threadIdx.x; i < NBINS; i += 256) h[i] = 0;
  __syncthreads();
  int ebase = blockIdx.x * BIN_CHUNK;
#pragma unroll
  for (int it = 0; it < BIN_CHUNK / 256; it++) {
    int e = ebase + it * 256 + threadIdx.x;
    int el; int l = edge_level(e, el);
    atomicAdd(&h[cLB[l] + (p.ii[l][el] >> 10)], 1);
  }
  __syncthreads();
  for (int b = threadIdx.x; b < NBINS; b += 256)
    p.hist[blockIdx.x * NBINS + b] = h[b];
}

__global__ void k_binT(BinP p) {
  __shared__ int sd[256];
  int b = blockIdx.x;
  int t = threadIdx.x;
  int carry = 0;
  for (int r = 0; r < 4; r++) {
    int idx = r * 256 + t;
    int v = (idx < NWG) ? p.hist[idx * NBINS + b] : 0;
    sd[t] = v;
    __syncthreads();
    for (int off = 1; off < 256; off <<= 1) {
      int x = sd[t];
      if (t >= off) x += sd[t - off];
      __syncthreads();
      sd[t] = x;
      __syncthreads();
    }
    if (idx < NWG) p.offs[b * NWG + idx] = carry + sd[t] - v;
    carry += sd[255];
    __syncthreads();
  }
  if (t == 0) p.total[b] = carry;
}

__global__ void k_binScan2(BinP p) {
  __shared__ int sd[256];
  int t = threadIdx.x;
  int v = (t < NBINS) ? p.total[t] : 0;
  sd[t] = v;
  __syncthreads();
  for (int off = 1; off < 256; off <<= 1) {
    int x = sd[t];
    if (t >= off) x += sd[t - off];
    __syncthreads();
    sd[t] = x;
    __syncthreads();
  }
  if (t < NBINS) p.base[t] = sd[t] - v;
  if (t == NBINS - 1) p.base[NBINS] = sd[t];
}

__global__ void k_binB(BinP p) {
  __shared__ int cur[NBINS];
  int wg = blockIdx.x;
  for (int b = threadIdx.x; b < NBINS; b += 256)
    cur[b] = p.base[b] + p.offs[b * NWG + wg];
  __syncthreads();
  int ebase = wg * BIN_CHUNK;
#pragma unroll
  for (int it = 0; it < BIN_CHUNK / 256; it++) {
    int e = ebase + it * 256 + threadIdx.x;
    int el; int l = edge_level(e, el);
    int i = p.ii[l][el], j = p.jj[l][el];
    int b = cLB[l] + (i >> 10);
    int gpos = atomicAdd(&cur[b], 1);
    p.pairs[gpos] = ((i & 1023) << 17) | j;
  }
}

__global__ void __launch_bounds__(256) k_binCSR(BinP p) {
  __shared__ int d[1024];
  __shared__ int sd[256];
  int lb; int l = blk_level(blockIdx.x, lb);
  int t = threadIdx.x;
  int e0g = p.base[blockIdx.x];
  int e1g = p.base[blockIdx.x + 1];
  int lvlbase = p.base[cLB[l]];
  int e0 = e0g - lvlbase;
  for (int i = t; i < 1024; i += 256) d[i] = 0;
  __syncthreads();
  for (int e = e0g + t; e < e1g; e += 256)
    atomicAdd(&d[p.pairs[e] >> 17], 1);
  __syncthreads();
  int a0 = d[4*t], a1 = d[4*t+1], a2 = d[4*t+2], a3 = d[4*t+3];
  int ts = a0 + a1 + a2 + a3;
  sd[t] = ts;
  __syncthreads();
  for (int off = 1; off < 256; off <<= 1) {
    int x = sd[t];
    if (t >= off) x += sd[t - off];
    __syncthreads();
    sd[t] = x;
    __syncthreads();
  }
  int c0 = e0 + sd[t] - ts;
  int c1 = c0 + a0, c2 = c1 + a1, c3 = c2 + a2;
  int* rp = p.rp[l];
  *(int4*)(rp + lb * 1024 + 4 * t) = make_int4(c0, c1, c2, c3);
  if (t == 0 && lb == cNB[l] - 1) rp[cNN[l]] = cNE[l];
  d[4*t] = c0; d[4*t+1] = c1; d[4*t+2] = c2; d[4*t+3] = c3;
  __syncthreads();
  int* col = p.col[l];
  for (int e = e0g + t; e < e1g; e += 256) {
    int pk = p.pairs[e];
    int slot = atomicAdd(&d[pk >> 17], 1);
    col[slot] = pk & 0x1FFFF;
  }
}

// ---------------- GEMM: out = act(in @ W + bias), one-pass, A-tile in LDS ----------------
template <int KIN, int KOUT, bool ELU>
__global__ void __launch_bounds__(256) k_gemm(const float* __restrict__ in,
                                              const float* __restrict__ W,
                                              const float* __restrict__ bias,
                                              float* __restrict__ out) {
  constexpr int CPT = KOUT / 4;
  __shared__ float As[KIN * 64];
  int rbase = blockIdx.x * 64;
  for (int idx = threadIdx.x; idx < 16 * KIN; idx += 256) {
    int r = idx / (KIN / 4);
    int q = idx - r * (KIN / 4);
    float4 v = *(const float4*)(in + (size_t)(rbase + r) * KIN + q * 4);
    As[(q * 4 + 0) * 64 + r] = v.x;
    As[(q * 4 + 1) * 64 + r] = v.y;
    As[(q * 4 + 2) * 64 + r] = v.z;
    As[(q * 4 + 3) * 64 + r] = v.w;
  }
  __syncthreads();
  int row = threadIdx.x & 63;
  int c0 = __builtin_amdgcn_readfirstlane((threadIdx.x >> 6) * CPT);
  float acc[CPT];
#pragma unroll
  for (int i = 0; i < CPT; i++) acc[i] = bias ? bias[c0 + i] : 0.f;
#pragma unroll 4
  for (int k = 0; k < KIN; k++) {
    float a = As[k * 64 + row];
    const float* wk = W + (size_t)k * KOUT + c0;   // uniform -> s_load
#pragma unroll
    for (int i = 0; i < CPT; i++) acc[i] += a * wk[i];
  }
  float* orow = out + (size_t)(rbase + row) * KOUT + c0;
#pragma unroll
  for (int u = 0; u < CPT / 4; u++) {
    float v0 = acc[4*u+0], v1 = acc[4*u+1], v2 = acc[4*u+2], v3 = acc[4*u+3];
    if (ELU) {
      v0 = v0 > 0.f ? v0 : expm1f(v0);  v1 = v1 > 0.f ? v1 : expm1f(v1);
      v2 = v2 > 0.f ? v2 : expm1f(v2);  v3 = v3 > 0.f ? v3 : expm1f(v3);
    }
    float4 o; o.x = v0; o.y = v1; o.z = v2; o.w = v3;
    *(float4*)(orow + 4 * u) = o;
  }
}

// ---------------- f = elu(h + CSR-gather-sum(hW)), float4 per thread ----------------
__global__ void k_agg_elu4(const float* __restrict__ h, const float* __restrict__ hW,
                           const int* __restrict__ rp, const int* __restrict__ col,
                           float* __restrict__ f, int n) {
  int gid = blockIdx.x * blockDim.x + threadIdx.x;
  if (gid >= n * (HID/4)) return;
  int v = gid / (HID/4);
  int c4 = (gid - v * (HID/4)) * 4;
  int e0 = rp[v], e1 = rp[v + 1];
  float4 s = *(const float4*)(h + (size_t)v*HID + c4);
  float* sp = (float*)&s;
  for (int e = e0; e < e1; e++) {
    int j = col[e];
    float4 x = *(const float4*)(hW + (size_t)j*HID + c4);
    sp[0] += x.x; sp[1] += x.y; sp[2] += x.z; sp[3] += x.w;
  }
#pragma unroll
  for (int i = 0; i < 4; i++) sp[i] = eluf(sp[i]);
  *(float4*)(f + (size_t)v*HID + c4) = s;
}

// ---------------- grouped segment-sum: up to 4 independent prop jobs per launch ----------------
// Body identical to the proven k_prop4; block finds its job via 3 compares.
struct PropJobs {
  const float* top[4]; const float* oldb[4];
  const int* rp[4]; const int* col[4];
  int half[4]; int n[4];
  int cum[4];          // cumulative block counts
  float* dst[4];
  int njobs;
};

__global__ void k_prop_multi(PropJobs J) {
  int b = blockIdx.x;
  int g = 0;
  if (J.njobs > 1 && b >= J.cum[0]) g = 1;
  if (J.njobs > 2 && b >= J.cum[1]) g = 2;
  if (J.njobs > 3 && b >= J.cum[2]) g = 3;
  int lb = g ? (b - J.cum[g - 1]) : b;
  int gid = lb * 256 + (int)threadIdx.x;
  int n = J.n[g];
  if (gid >= n * (HID/4)) return;
  int v = gid / (HID/4);
  int c4 = (gid - v * (HID/4)) * 4;
  const int* rp = J.rp[g];
  const int* col = J.col[g];
  const float* top = J.top[g];
  const float* oldb = J.oldb[g];
  int half = J.half[g];
  int e0 = rp[v], e1 = rp[v + 1];
  float4 s = {0,0,0,0};
  float* sp = (float*)&s;
  for (int e = e0; e < e1; e++) {
    int j = col[e];
    const float* src = (j < half) ? top : oldb;
    float4 x = *(const float4*)(src + (size_t)j*HID + c4);
    sp[0] += x.x; sp[1] += x.y; sp[2] += x.z; sp[3] += x.w;
  }
  *(float4*)(J.dst[g] + (size_t)v*HID + c4) = s;
}

// ---------------- finalize bn2 (parallel) and fold into Wc ----------------
__global__ void k_fin_bn2(const float* __restrict__ pacc, int npart,
                          const float* __restrict__ g, const float* __restrict__ b,
                          const float* __restrict__ Wc, float* __restrict__ wcp) {
  __shared__ float red[128];
  __shared__ float sc[64], sh[64];
  int t = threadIdx.x;           // 1024
  int c2 = t & 127;
  int sub = t >> 7;              // 0..7
  float s = 0.f;
  for (int p = sub; p < npart; p += 8) s += pacc[p * 128 + c2];
  if (t < 128) red[t] = 0.f;
  __syncthreads();
  atomicAdd(&red[c2], s);
  __syncthreads();
  if (t < 64) {
    float invn = 1.f / (float)cN0;
    float m = red[t] * invn;
    float v = red[64 + t] * invn - m * m;
    float scv = g[t] * rsqrtf(v + 1e-5f);
    sc[t] = scv;
    sh[t] = b[t] - m * scv;
  }
  __syncthreads();
  for (int i = t; i < 64 * 13; i += 1024) { int c = i / 13; wcp[i] = sc[c] * Wc[i]; }
  if (t < 13) {
    float acc13 = 0.f;
    for (int c = 0; c < 64; c++) acc13 += sh[c] * Wc[c*13 + t];
    wcp[64*13 + t] = acc13;
  }
}

// ---------------- final: out = bn2(x3) @ Wc  == x3 @ Wc' + bias13 ----------------
__global__ void k_final(const float* __restrict__ x3, const float* __restrict__ wcp,
                        float* __restrict__ out) {
  __shared__ float Wl[64*13 + 13];
  for (int i = threadIdx.x; i < 64*13 + 13; i += blockDim.x) Wl[i] = wcp[i];
  __syncthreads();
  int gid = blockIdx.x * blockDim.x + threadIdx.x; // exactly N0*13
  int r = gid / 13, o = gid - r * 13;
  const float* row = x3 + (size_t)r * 64;
  float s = Wl[64*13 + o];
#pragma unroll
  for (int c = 0; c < 64; c++) s += row[c] * Wl[c*13 + o];
  out[gid] = s;
}

// ===========================================================================
extern "C" void kernel_launch(void* const* d_in, const int* in_sizes, int n_in,
                              void* d_out, int out_size, void* d_ws, size_t ws_size,
                              hipStream_t stream) {
  const float* feat   = (const float*)d_in[0];
  const float* bn1_g  = (const float*)d_in[1];
  const float* W_emb  = (const float*)d_in[3];
  const float* embn_g = (const float*)d_in[4];
  const float* embn_b = (const float*)d_in[5];
  const float* W_msg  = (const float*)d_in[6];
  const float* W1 = (const float*)d_in[7];
  const float* b1 = (const float*)d_in[8];
  const float* W2 = (const float*)d_in[9];
  const float* b2 = (const float*)d_in[10];
  const float* W3 = (const float*)d_in[11];
  const float* b3 = (const float*)d_in[12];
  const float* bn2_g = (const float*)d_in[13];
  const float* bn2_b = (const float*)d_in[14];
  const float* Wc    = (const float*)d_in[15];

  const int NNODE[4] = {131072, 65536, 32768, 16384};
  const int NEDGE[4] = {917504, 458752, 229376, 114688};   // host copy (R11 lesson)
  const int N = cN0;
  const int SBLK = 256;   // colstats partial blocks
  const int BN1B = 64;    // bn1 partial blocks

  // ---- workspace arena (256B-aligned) ----
  size_t off = 0;
  char* base = (char*)d_ws;
  auto af = [&](size_t nf) -> float* { float* p = (float*)(base + off); off += ((nf*4 + 255) & ~(size_t)255); return p; };
  auto ai = [&](size_t ni) -> int*   { int*   p = (int*)  (base + off); off += ((ni*4 + 255) & ~(size_t)255); return p; };

  int* hist   = ai((size_t)NWG * NBINS);
  int* offs   = ai((size_t)NBINS * NWG);
  int* total  = ai(NBINS);
  int* bbase  = ai(NBINS + 1);
  int* pairs  = ai(NEDGE_TOT);

  float* pacc1 = af((size_t)BN1B * 27);
  float* pacc2 = af((size_t)SBLK * 128);
  float* fw  = af(6*HID + HID);
  float* wcp = af(64*13 + 13);
  int* rp[4];   for (int l = 0; l < 4; l++) rp[l]   = ai(NNODE[l] + 1);
  int* col[4];  for (int l = 0; l < 4; l++) col[l]  = ai(NEDGE[l]);

  float* t_h0 = af((size_t)N * HID);     // h; later hud0 ping (H0P)
  float* hWb  = af((size_t)N * HID);     // hW per level; later hud0 pong (H0Q)
  float* f[4];
  f[0] = af((size_t)NNODE[0] * HID);
  f[1] = af((size_t)NNODE[1] * HID);
  f[2] = af((size_t)NNODE[2] * HID);
  f[3] = af((size_t)NNODE[3] * HID);
  float* h1a = af((size_t)NNODE[1] * HID);
  float* h1b = af((size_t)NNODE[1] * HID);
  float* h2a = af((size_t)NNODE[2] * HID);
  float* h2b = af((size_t)NNODE[2] * HID);
  float* h3  = af((size_t)NNODE[3] * HID);

  float* x1 = f[0];           // N*64 fits in f0's N*80
  float* x2 = f[1];           // N*64 fits in f1+f2+f3 span
  float* x3 = f[0];
  (void)ws_size; (void)in_sizes; (void)n_in; (void)out_size;

  // ---- bn1 moments -> analytic fold -> fused embedding (h = relu(feat@fw+b)) ----
  k_bn1_stats<<<BN1B, 256, 0, stream>>>(feat, pacc1);
  k_fold<<<1, 256, 0, stream>>>(pacc1, BN1B, bn1_g, embn_g, embn_b, W_emb, fw);
  k_emb4<<<(N * (HID/4)) / 256, 256, 0, stream>>>(feat, fw, t_h0);

  // ---- binned CSR build, deterministic: 5 launches, no global atomics ----
  BinP bp;
  for (int l = 0; l < 4; l++) {
    bp.ii[l] = (const int*)d_in[16 + 2*l];
    bp.jj[l] = (const int*)d_in[17 + 2*l];
    bp.rp[l] = rp[l]; bp.col[l] = col[l];
  }
  bp.hist = hist; bp.offs = offs; bp.total = total; bp.base = bbase; bp.pairs = pairs;
  k_binA<<<NWG, 256, 0, stream>>>(bp);
  k_binT<<<NBINS, 256, 0, stream>>>(bp);
  k_binScan2<<<1, 256, 0, stream>>>(bp);
  k_binB<<<NWG, 256, 0, stream>>>(bp);
  k_binCSR<<<NBINS, 256, 0, stream>>>(bp);

  // ---- features per level: hW = h @ W_msg[l]; f = elu(h + csr_sum(hW)) ----
  const float* hin = t_h0;
  for (int l = 0; l < 4; l++) {
    int n = NNODE[l];
    k_gemm<80, 80, false><<<n / 64, 256, 0, stream>>>(hin, W_msg + (size_t)l * HID * HID, nullptr, hWb);
    k_agg_elu4<<<(n * (HID/4)) / 256, 256, 0, stream>>>(hin, hWb, rp[l], col[l], f[l], n);
    hin = f[l];
  }

  // ---- propagation: 10 segment-sums grouped into 4 launches by dep level ----
  float* H0P = t_h0;  // h0 dead after features phase
  float* H0Q = hWb;   // hW dead after features phase
  auto nb = [](int n) { return (n * (HID/4)) / 256; };

  PropJobs g1{};  // P1(l0,f0), P2(l1,f1), P4(l2,f2), P7(l3,f3)
  g1.njobs = 4;
  g1.top[0]=f[0]; g1.oldb[0]=f[0]; g1.half[0]=NNODE[0]; g1.rp[0]=rp[0]; g1.col[0]=col[0]; g1.dst[0]=H0P; g1.n[0]=NNODE[0];
  g1.top[1]=f[1]; g1.oldb[1]=f[1]; g1.half[1]=NNODE[1]; g1.rp[1]=rp[1]; g1.col[1]=col[1]; g1.dst[1]=h1a; g1.n[1]=NNODE[1];
  g1.top[2]=f[2]; g1.oldb[2]=f[2]; g1.half[2]=NNODE[2]; g1.rp[2]=rp[2]; g1.col[2]=col[2]; g1.dst[2]=h2a; g1.n[2]=NNODE[2];
  g1.top[3]=f[3]; g1.oldb[3]=f[3]; g1.half[3]=NNODE[3]; g1.rp[3]=rp[3]; g1.col[3]=col[3]; g1.dst[3]=h3;  g1.n[3]=NNODE[3];
  g1.cum[0]=nb(NNODE[0]); g1.cum[1]=g1.cum[0]+nb(NNODE[1]); g1.cum[2]=g1.cum[1]+nb(NNODE[2]); g1.cum[3]=g1.cum[2]+nb(NNODE[3]);
  k_prop_multi<<<g1.cum[3], 256, 0, stream>>>(g1);

  PropJobs g2{};  // P3(l0: h1a|H0P), P5(l1: h2a|h1a), P8(l2: h3|h2a)
  g2.njobs = 3;
  g2.top[0]=h1a; g2.oldb[0]=H0P; g2.half[0]=65536; g2.rp[0]=rp[0]; g2.col[0]=col[0]; g2.dst[0]=H0Q; g2.n[0]=NNODE[0];
  g2.top[1]=h2a; g2.oldb[1]=h1a; g2.half[1]=32768; g2.rp[1]=rp[1]; g2.col[1]=col[1]; g2.dst[1]=h1b; g2.n[1]=NNODE[1];
  g2.top[2]=h3;  g2.oldb[2]=h2a; g2.half[2]=16384; g2.rp[2]=rp[2]; g2.col[2]=col[2]; g2.dst[2]=h2b; g2.n[2]=NNODE[2];
  g2.cum[0]=nb(NNODE[0]); g2.cum[1]=g2.cum[0]+nb(NNODE[1]); g2.cum[2]=g2.cum[1]+nb(NNODE[2]);
  k_prop_multi<<<g2.cum[2], 256, 0, stream>>>(g2);

  PropJobs g3{};  // P6(l0: h1b|H0Q), P9(l1: h2b|h1b)
  g3.njobs = 2;
  g3.top[0]=h1b; g3.oldb[0]=H0Q; g3.half[0]=65536; g3.rp[0]=rp[0]; g3.col[0]=col[0]; g3.dst[0]=H0P; g3.n[0]=NNODE[0];
  g3.top[1]=h2b; g3.oldb[1]=h1b; g3.half[1]=32768; g3.rp[1]=rp[1]; g3.col[1]=col[1]; g3.dst[1]=h1a; g3.n[1]=NNODE[1];
  g3.cum[0]=nb(NNODE[0]); g3.cum[1]=g3.cum[0]+nb(NNODE[1]);
  k_prop_multi<<<g3.cum[1], 256, 0, stream>>>(g3);

  PropJobs g4{};  // P10(l0: h1a|H0P)
  g4.njobs = 1;
  g4.top[0]=h1a; g4.oldb[0]=H0P; g4.half[0]=65536; g4.rp[0]=rp[0]; g4.col[0]=col[0]; g4.dst[0]=H0Q; g4.n[0]=NNODE[0];
  g4.cum[0]=nb(NNODE[0]);
  k_prop_multi<<<g4.cum[0], 256, 0, stream>>>(g4);
  // final h_up_down == H0Q

  // ---- MLP head + bn2 folded into Wc ----
  k_gemm<80, 64, true><<<N / 64, 256, 0, stream>>>(H0Q, W1, b1, x1);
  k_gemm<64, 64, true><<<N / 64, 256, 0, stream>>>(x1, W2, b2, x2);
  k_gemm<64, 64, true><<<N / 64, 256, 0, stream>>>(x2, W3, b3, x3);
  k_colstats<<<SBLK, 256, 2*64*4, stream>>>(x3, N, 64, pacc2);
  k_fin_bn2<<<1, 1024, 0, stream>>>(pacc2, SBLK, bn2_g, bn2_b, Wc, wcp);
  k_final<<<(N * 13) / 256, 256, 0, stream>>>(x3, wcp, (float*)d_out);
}